// Round 1
// baseline (385.403 us; speedup 1.0000x reference)
//
#include <hip/hip_runtime.h>

// ---------------------------------------------------------------------------
// MozafariMNIST2018 SNN forward (training branch, max_layer==2) for MI355X.
//
// Pipeline:
//  1. memset d_out (final spk/pot are >=99.6% zeros) and spk_in padding.
//  2. prep_wt:   transpose w2 [250][270] -> Wt [270][256] (f-padded with 0).
//  3. conv1:     conv(5x5)+fire(15)+maxpool(2x2 = OR)+pad -> spk_in (15,30,82,82)
//  4. conv2:     implicit GEMM; per (t,h,w) emit max_f / argmax_f of
//                thresholded potentials only (pointwise inhibition keeps <=1
//                feature per position, so raw pot2 (96MB) is never stored).
//  5. winmap:    earliest-spike winner channel per (h,w), gated by clamp[T-1].
//  6. recompute: winner-channel potentials (15,80,80) via direct conv (tiny).
//  7. winners:   compacted get_k_winners (8 argmax+suppress rounds) in 1 block.
//  8. scatter:   sparse write of spk/pot winner entries into zeroed d_out.
// ---------------------------------------------------------------------------

#define T_STEPS 15

// ws layout (float offsets)
#define WT_OFF      0            // 270*256      = 69120
#define SPKIN_OFF   69120        // 15*30*82*82  = 3025800
#define MAXV_OFF    3094920      // 15*80*80     = 96000
#define ARGM_OFF    3190920      // 96000 (int)
#define WINMAP_OFF  3286920      // 6400 (int)
#define POTWIN_OFF  3293320      // 96000
// total 3389320 floats = 13.56 MB

// ---------------------------------------------------------------------------
__global__ __launch_bounds__(256) void prep_wt_kernel(
    const float* __restrict__ w2, float* __restrict__ Wt) {
  int k = blockIdx.x;          // 0..269
  int f = threadIdx.x;         // 0..255
  Wt[k * 256 + f] = (f < 250) ? w2[f * 270 + k] : 0.f;
}

// ---------------------------------------------------------------------------
// conv1 + fire(15) + maxpool(2,2) + pad(1) -> spk_in[t][c][82][82]
// grid: 15 t * 25 tiles (16x16 pooled each), block 256 = 16x16 pooled pos.
__global__ __launch_bounds__(256) void conv1_kernel(
    const int* __restrict__ xin, const float* __restrict__ w1,
    float* __restrict__ spk_in) {
  __shared__ float patch[6 * 36 * 36];   // input window (padded coords)
  __shared__ float w1s[30 * 150];

  int tid = threadIdx.x;
  int b = blockIdx.x;
  int t = b / 25, tile = b % 25;
  int py0 = (tile / 5) * 16, px0 = (tile % 5) * 16;

  for (int idx = tid; idx < 6 * 36 * 36; idx += 256) {
    int c = idx / 1296, rem = idx % 1296;
    int r = rem / 36, col = rem % 36;
    int gy = 2 * py0 + r - 2, gx = 2 * px0 + col - 2;   // unpadded coords
    float v = 0.f;
    if ((unsigned)gy < 160u && (unsigned)gx < 160u)
      v = (float)xin[((t * 6 + c) * 160 + gy) * 160 + gx];
    patch[idx] = v;
  }
  for (int idx = tid; idx < 4500; idx += 256) w1s[idx] = w1[idx];
  __syncthreads();

  int py = tid >> 4, px = tid & 15;
  int ybase = 2 * py, xbase = 2 * px;

  for (int fc = 0; fc < 5; ++fc) {       // 5 chunks of 6 features
    float acc[6][4];
#pragma unroll
    for (int i = 0; i < 6; ++i) {
      acc[i][0] = acc[i][1] = acc[i][2] = acc[i][3] = 0.f;
    }
    for (int c = 0; c < 6; ++c) {
      float pr[6][6];
#pragma unroll
      for (int a = 0; a < 6; ++a)
#pragma unroll
        for (int bb = 0; bb < 6; ++bb)
          pr[a][bb] = patch[c * 1296 + (ybase + a) * 36 + xbase + bb];
      const float* wb = &w1s[(fc * 6) * 150 + c * 25];
#pragma unroll
      for (int fi = 0; fi < 6; ++fi) {
        const float* wf = wb + fi * 150;
#pragma unroll
        for (int ky = 0; ky < 5; ++ky)
#pragma unroll
          for (int kx = 0; kx < 5; ++kx) {
            float wv = wf[ky * 5 + kx];
            acc[fi][0] = fmaf(wv, pr[ky][kx],         acc[fi][0]);
            acc[fi][1] = fmaf(wv, pr[ky][kx + 1],     acc[fi][1]);
            acc[fi][2] = fmaf(wv, pr[ky + 1][kx],     acc[fi][2]);
            acc[fi][3] = fmaf(wv, pr[ky + 1][kx + 1], acc[fi][3]);
          }
      }
    }
#pragma unroll
    for (int fi = 0; fi < 6; ++fi) {
      int f = fc * 6 + fi;
      bool sp = (acc[fi][0] >= 15.f) | (acc[fi][1] >= 15.f) |
                (acc[fi][2] >= 15.f) | (acc[fi][3] >= 15.f);
      spk_in[((t * 30 + f) * 82 + (1 + py0 + py)) * 82 + (1 + px0 + px)] =
          sp ? 1.f : 0.f;
    }
  }
}

// ---------------------------------------------------------------------------
// conv2 implicit GEMM. grid: 15 t * 100 tiles (8x8 pos), block 256.
// Emits per (t,h,w): max_f(thresholded pot), argmax_f (first-max).
__global__ __launch_bounds__(256) void conv2_kernel(
    const float* __restrict__ spk_in, const float* __restrict__ Wt,
    float* __restrict__ maxv_ws, int* __restrict__ argm_ws) {
  __shared__ float Xc[135 * 64];        // half-K im2col (34.6 KB)

  int tid = threadIdx.x;
  int b = blockIdx.x;
  int t = b / 100, tile = b % 100;
  int y0 = (tile / 10) * 8, x0 = (tile % 10) * 8;
  int quad = tid & 15, fg = tid >> 4;   // 16 pos-quads x 16 f-groups

  float acc[64];
#pragma unroll
  for (int i = 0; i < 64; ++i) acc[i] = 0.f;

  const float* wtb = Wt + fg * 16;
  for (int ph = 0; ph < 2; ++ph) {
    for (int idx = tid; idx < 135 * 64; idx += 256) {
      int kk = idx >> 6, p = idx & 63;
      int k = ph * 135 + kk;
      int c = k / 9, r9 = k % 9;
      int ky = r9 / 3, kx = r9 % 3;
      int py = p >> 3, px = p & 7;
      Xc[idx] = spk_in[((t * 30 + c) * 82 + (y0 + py + ky)) * 82 +
                       (x0 + px + kx)];
    }
    __syncthreads();
    const float* wp = wtb + ph * 135 * 256;
    for (int kk = 0; kk < 135; ++kk) {
      float4 xv4 = *(const float4*)(Xc + kk * 64 + quad * 4);
      float xq[4] = {xv4.x, xv4.y, xv4.z, xv4.w};
      float wv[16];
      *(float4*)(wv + 0)  = *(const float4*)(wp + kk * 256 + 0);
      *(float4*)(wv + 4)  = *(const float4*)(wp + kk * 256 + 4);
      *(float4*)(wv + 8)  = *(const float4*)(wp + kk * 256 + 8);
      *(float4*)(wv + 12) = *(const float4*)(wp + kk * 256 + 12);
#pragma unroll
      for (int i = 0; i < 16; ++i)
#pragma unroll
        for (int j = 0; j < 4; ++j)
          acc[i * 4 + j] = fmaf(wv[i], xq[j], acc[i * 4 + j]);
    }
    __syncthreads();
  }

  // epilogue: fire(10) threshold, then per-position max/argmax over f
  float mv[4]; int mi[4];
#pragma unroll
  for (int j = 0; j < 4; ++j) { mv[j] = -1.f; mi[j] = 0; }
#pragma unroll
  for (int i = 0; i < 16; ++i) {
    int f = fg * 16 + i;
#pragma unroll
    for (int j = 0; j < 4; ++j) {
      float v = acc[i * 4 + j];
      v = (v >= 10.f) ? v : 0.f;
      if (v > mv[j]) { mv[j] = v; mi[j] = f; }   // strict > => first-max
    }
  }
  float* redv = Xc;                       // reuse LDS (post-sync)
  int*   redi = (int*)(Xc + 64 * 17);
#pragma unroll
  for (int j = 0; j < 4; ++j) {
    int p = quad * 4 + j;
    redv[p * 17 + fg] = mv[j];
    redi[p * 17 + fg] = mi[j];
  }
  __syncthreads();
  if (tid < 64) {
    int p = tid;
    float bv = -1.f; int bf = 0;
#pragma unroll
    for (int g = 0; g < 16; ++g) {        // fg ascending = f ascending
      float v = redv[p * 17 + g];
      if (v > bv) { bv = v; bf = redi[p * 17 + g]; }
    }
    int h = y0 + (p >> 3), w = x0 + (p & 7);
    int pos = h * 80 + w;
    maxv_ws[t * 6400 + pos] = bv;
    argm_ws[t * 6400 + pos] = bf;
  }
}

// ---------------------------------------------------------------------------
// per-(h,w) winner channel (pointwise inhibition bookkeeping)
__global__ __launch_bounds__(256) void winmap_kernel(
    const float* __restrict__ maxv, const int* __restrict__ argm,
    int* __restrict__ winmap) {
  int pos = blockIdx.x * 256 + threadIdx.x;
  if (pos >= 6400) return;
  int nc = 0;
#pragma unroll
  for (int t = 0; t < T_STEPS; ++t) nc += (maxv[t * 6400 + pos] > 0.f) ? 1 : 0;
  int e = T_STEPS - nc; if (e > 14) e = 14;        // clip(T - sum, 0, T-1)
  int win = argm[e * 6400 + pos];
  bool gate = maxv[14 * 6400 + pos] > 0.f;         // clamp[-1]
  winmap[pos] = gate ? win : -1;
}

// ---------------------------------------------------------------------------
// recompute winner-channel potentials: potwin[t][pos] (thresholded)
__global__ __launch_bounds__(256) void recompute_kernel(
    const float* __restrict__ spk_in, const float* __restrict__ w2,
    const int* __restrict__ winmap, float* __restrict__ potwin) {
  int idx = blockIdx.x * 256 + threadIdx.x;        // < 96000
  int pos = idx % 6400, t = idx / 6400;
  int win = winmap[pos];
  float p = 0.f;
  if (win >= 0) {
    int h = pos / 80, w = pos % 80;
    const float* wt = w2 + win * 270;
    const float* base = spk_in + t * 30 * 6724;
    float a = 0.f;
    for (int c = 0; c < 30; ++c) {
#pragma unroll
      for (int ky = 0; ky < 3; ++ky)
#pragma unroll
        for (int kx = 0; kx < 3; ++kx)
          a = fmaf(wt[c * 9 + ky * 3 + kx],
                   base[c * 6724 + (h + ky) * 82 + (w + kx)], a);
    }
    p = (a >= 10.f) ? a : 0.f;
  }
  potwin[idx] = p;
}

// ---------------------------------------------------------------------------
// get_k_winners on compacted (<=6400) entries; writes 8x3 winners as floats.
__global__ __launch_bounds__(1024) void winners_kernel(
    const int* __restrict__ winmap, const float* __restrict__ potwin,
    float* __restrict__ out_win) {
  __shared__ float tv[6400];
  __shared__ int   tf[6400];
  __shared__ float redv[1024];
  __shared__ int   redk[1024];
  __shared__ int   sh_w[4];   // f, r, c, valid

  int tid = threadIdx.x;

  // phase 1: per-position value at first-spike time + global trunc-max
  float localmax = 0.f;
  for (int pos = tid; pos < 6400; pos += 1024) {
    int win = winmap[pos];
    float val = 0.f; int nspk = 0;
    if (win >= 0) {
#pragma unroll
      for (int t = 0; t < T_STEPS; ++t)
        nspk += (potwin[t * 6400 + pos] > 0.f) ? 1 : 0;
      int first = T_STEPS - nspk; if (first > 14) first = 14;
      val = potwin[first * 6400 + pos];
      if (nspk > 0 && val > localmax) localmax = val;
    }
    tv[pos] = val;
    tf[pos] = ((win + 1) << 4) | nspk;   // pack: win in [-1,249], nspk in [0,15]
  }
  redv[tid] = localmax;
  __syncthreads();
  for (int s = 512; s > 0; s >>= 1) {
    if (tid < s) redv[tid] = fmaxf(redv[tid], redv[tid + s]);
    __syncthreads();
  }
  float v = redv[0] * (float)T_STEPS;
  __syncthreads();

  // phase 2: totals = nspk * (val + v)
  for (int pos = tid; pos < 6400; pos += 1024) {
    int meta = tf[pos];
    int win = (meta >> 4) - 1, nspk = meta & 15;
    tf[pos] = win;
    tv[pos] = (win >= 0) ? (float)nspk * (tv[pos] + v) : 0.f;
  }
  __syncthreads();

  // phase 3: 8 rounds of argmax (value desc, flat-index asc) + suppression
  for (int it = 0; it < 8; ++it) {
    float bv = -1.f; int bk = 0x7fffffff;
    for (int pos = tid; pos < 6400; pos += 1024) {
      float tvv = tv[pos];
      int key = tf[pos] * 6400 + pos;    // flat index in (F,H,W)
      if (tvv > bv || (tvv == bv && key < bk)) { bv = tvv; bk = key; }
    }
    redv[tid] = bv; redk[tid] = bk;
    __syncthreads();
    for (int s = 512; s > 0; s >>= 1) {
      if (tid < s) {
        float ov = redv[tid + s]; int ok = redk[tid + s];
        if (ov > redv[tid] || (ov == redv[tid] && ok < redk[tid])) {
          redv[tid] = ov; redk[tid] = ok;
        }
      }
      __syncthreads();
    }
    if (tid == 0) {
      float mx = redv[0];
      int f = -1, r = -1, c = -1, valid = 0;
      if (mx != 0.f) {
        int key = redk[0];
        f = key / 6400; int pos = key % 6400;
        r = pos / 80; c = pos % 80;
        valid = 1;
      }
      out_win[it * 3 + 0] = (float)f;
      out_win[it * 3 + 1] = (float)r;
      out_win[it * 3 + 2] = (float)c;
      sh_w[0] = f; sh_w[1] = r; sh_w[2] = c; sh_w[3] = valid;
    }
    __syncthreads();
    if (sh_w[3]) {
      int wf = sh_w[0], wr = sh_w[1], wc = sh_w[2];
      for (int pos = tid; pos < 6400; pos += 1024) {
        int r = pos / 80, c = pos % 80;
        int dr = r - wr; if (dr < 0) dr = -dr;
        int dc = c - wc; if (dc < 0) dc = -dc;
        if (tf[pos] == wf || (dr <= 1 && dc <= 1)) tv[pos] = 0.f;
      }
    }
    __syncthreads();
  }
}

// ---------------------------------------------------------------------------
// sparse scatter of final spk/pot into zeroed d_out
__global__ __launch_bounds__(256) void scatter_kernel(
    const int* __restrict__ winmap, const float* __restrict__ potwin,
    float* __restrict__ out) {
  int pos = blockIdx.x * 256 + threadIdx.x;
  if (pos >= 6400) return;
  int win = winmap[pos];
  if (win < 0) return;
#pragma unroll
  for (int t = 0; t < T_STEPS; ++t) {
    float p = potwin[t * 6400 + pos];
    int o = (t * 250 + win) * 6400 + pos;
    out[o] = (p > 0.f) ? 1.f : 0.f;       // spk
    out[24000000 + o] = p;                // pot
  }
}

// ---------------------------------------------------------------------------
extern "C" void kernel_launch(void* const* d_in, const int* in_sizes, int n_in,
                              void* d_out, int out_size, void* d_ws,
                              size_t ws_size, hipStream_t stream) {
  const int*   xin = (const int*)d_in[0];
  const float* w1  = (const float*)d_in[1];
  const float* w2  = (const float*)d_in[2];
  float* out = (float*)d_out;
  float* ws  = (float*)d_ws;

  float* Wt     = ws + WT_OFF;
  float* spk_in = ws + SPKIN_OFF;
  float* maxv   = ws + MAXV_OFF;
  int*   argm   = (int*)(ws + ARGM_OFF);
  int*   winmap = (int*)(ws + WINMAP_OFF);
  float* potwin = ws + POTWIN_OFF;

  hipMemsetAsync(d_out, 0, (size_t)out_size * sizeof(float), stream);
  hipMemsetAsync(spk_in, 0, (size_t)3025800 * sizeof(float), stream);

  prep_wt_kernel  <<<270,  256, 0, stream>>>(w2, Wt);
  conv1_kernel    <<<375,  256, 0, stream>>>(xin, w1, spk_in);
  conv2_kernel    <<<1500, 256, 0, stream>>>(spk_in, Wt, maxv, argm);
  winmap_kernel   <<<25,   256, 0, stream>>>(maxv, argm, winmap);
  recompute_kernel<<<375,  256, 0, stream>>>(spk_in, w2, winmap, potwin);
  winners_kernel  <<<1,   1024, 0, stream>>>(winmap, potwin, out + 48000000);
  scatter_kernel  <<<25,   256, 0, stream>>>(winmap, potwin, out);
}

// Round 2
// 232.540 us; speedup vs baseline: 1.6574x; 1.6574x over previous
//
#include <hip/hip_runtime.h>

// ---------------------------------------------------------------------------
// MozafariMNIST2018 SNN forward (training branch, max_layer==2) for MI355X.
//
//  conv2 (the hot spot) now runs on the matrix cores: binary bf16 activations
//  x (hi+lo) bf16-split weights, fp32 MFMA accumulate. Only per-(t,h,w)
//  max/argmax over f leave the kernel; output values are recomputed exactly
//  in fp32 scalar for the (sparse) winner channels.
// ---------------------------------------------------------------------------

typedef unsigned short u16;
typedef __attribute__((ext_vector_type(8))) short short8;
typedef __attribute__((ext_vector_type(4))) float f32x4;

#define T_STEPS 15

// ws layout (byte offsets), all 16B aligned
#define WHI_OFF     0u         // 256*288 u16 = 147456 B
#define WLO_OFF     147456u    // 147456 B
#define SPKIN_OFF   294912u    // 15*30*82*82 u16 = 6051600 B
#define MAXV_OFF    6346512u   // 96000 f32
#define ARGM_OFF    6730512u   // 96000 i32
#define WINMAP_OFF  7114512u   // 6400 i32
#define POTWIN_OFF  7140112u   // 96000 f32 -> end 7524112

static __device__ __forceinline__ u16 f2bf_rne(float f) {
  unsigned u = __float_as_uint(f);
  unsigned r = u + 0x7FFFu + ((u >> 16) & 1u);
  return (u16)(r >> 16);
}
static __device__ __forceinline__ float bf2f(u16 b) {
  return __uint_as_float(((unsigned)b) << 16);
}

// ---------------------------------------------------------------------------
// w2 [250][270] fp32 -> Whi/Wlo [256][288] bf16 (f,k zero-padded)
__global__ __launch_bounds__(256) void prep_wt_kernel(
    const float* __restrict__ w2, u16* __restrict__ Whi,
    u16* __restrict__ Wlo) {
  int g = blockIdx.x * 256 + threadIdx.x;   // < 73728
  int f = g / 288, k = g % 288;
  u16 h = 0, l = 0;
  if (f < 250 && k < 270) {
    float w = w2[f * 270 + k];
    h = f2bf_rne(w);
    l = f2bf_rne(w - bf2f(h));
  }
  Whi[g] = h;
  Wlo[g] = l;
}

// ---------------------------------------------------------------------------
// conv1 + fire(15) + maxpool(2,2 = OR) + pad(1) -> spk_in[t][c][82][82] (bf16)
__global__ __launch_bounds__(256) void conv1_kernel(
    const int* __restrict__ xin, const float* __restrict__ w1,
    u16* __restrict__ spk_in) {
  __shared__ float patch[6 * 36 * 36];
  __shared__ float w1s[30 * 150];

  int tid = threadIdx.x;
  int b = blockIdx.x;
  int t = b / 25, tile = b % 25;
  int py0 = (tile / 5) * 16, px0 = (tile % 5) * 16;

  for (int idx = tid; idx < 6 * 36 * 36; idx += 256) {
    int c = idx / 1296, rem = idx % 1296;
    int r = rem / 36, col = rem % 36;
    int gy = 2 * py0 + r - 2, gx = 2 * px0 + col - 2;
    float v = 0.f;
    if ((unsigned)gy < 160u && (unsigned)gx < 160u)
      v = (float)xin[((t * 6 + c) * 160 + gy) * 160 + gx];
    patch[idx] = v;
  }
  for (int idx = tid; idx < 4500; idx += 256) w1s[idx] = w1[idx];
  __syncthreads();

  int py = tid >> 4, px = tid & 15;
  int ybase = 2 * py, xbase = 2 * px;

  for (int fc = 0; fc < 5; ++fc) {
    float acc[6][4];
#pragma unroll
    for (int i = 0; i < 6; ++i)
      acc[i][0] = acc[i][1] = acc[i][2] = acc[i][3] = 0.f;
    for (int c = 0; c < 6; ++c) {
      float pr[6][6];
#pragma unroll
      for (int a = 0; a < 6; ++a)
#pragma unroll
        for (int bb = 0; bb < 6; ++bb)
          pr[a][bb] = patch[c * 1296 + (ybase + a) * 36 + xbase + bb];
      const float* wb = &w1s[(fc * 6) * 150 + c * 25];
#pragma unroll
      for (int fi = 0; fi < 6; ++fi) {
        const float* wf = wb + fi * 150;
#pragma unroll
        for (int ky = 0; ky < 5; ++ky)
#pragma unroll
          for (int kx = 0; kx < 5; ++kx) {
            float wv = wf[ky * 5 + kx];
            acc[fi][0] = fmaf(wv, pr[ky][kx],         acc[fi][0]);
            acc[fi][1] = fmaf(wv, pr[ky][kx + 1],     acc[fi][1]);
            acc[fi][2] = fmaf(wv, pr[ky + 1][kx],     acc[fi][2]);
            acc[fi][3] = fmaf(wv, pr[ky + 1][kx + 1], acc[fi][3]);
          }
      }
    }
#pragma unroll
    for (int fi = 0; fi < 6; ++fi) {
      int f = fc * 6 + fi;
      bool sp = (acc[fi][0] >= 15.f) | (acc[fi][1] >= 15.f) |
                (acc[fi][2] >= 15.f) | (acc[fi][3] >= 15.f);
      spk_in[((t * 30 + f) * 82 + (1 + py0 + py)) * 82 + (1 + px0 + px)] =
          sp ? (u16)0x3F80 : (u16)0;
    }
  }
}

// ---------------------------------------------------------------------------
// conv2 implicit-GEMM MFMA. grid 15*100, block 256 (4 waves).
// Block tile: 256 f (padded) x 64 pos (8x8), K = 288 (9 MFMA steps), hi+lo.
// Emits per (t,h,w): max_f / argmax_f of thresholded potentials.
__global__ __launch_bounds__(256) void conv2_kernel(
    const u16* __restrict__ spk_in, const u16* __restrict__ Whi,
    const u16* __restrict__ Wlo, float* __restrict__ maxv_ws,
    int* __restrict__ argm_ws) {
  __shared__ __align__(16) u16 lds[64 * 320 + 3008];  // Xt (swizzled) + patch
  u16* Xt = lds;
  u16* patch = lds + 20480;

  int tid = threadIdx.x;
  int b = blockIdx.x;
  int t = b / 100, tile = b % 100;
  int y0 = (tile / 10) * 8, x0 = (tile % 10) * 8;

  // stage raw 30x10x10 patch (bf16 spikes)
  const u16* sb = spk_in + (size_t)t * 30 * 6724;
  for (int idx = tid; idx < 3000; idx += 256) {
    int c = idx / 100, rem = idx % 100;
    int dy = rem / 10, dx = rem % 10;
    patch[idx] = sb[c * 6724 + (y0 + dy) * 82 + (x0 + dx)];
  }
  __syncthreads();

  // build im2col Xt[p=64][K=288 pad 320] with XOR swizzle (bank-conflict fix)
  for (int task = tid; task < 2304; task += 256) {
    int p = task / 36, g = task % 36;
    int py = p >> 3, px = p & 7;
    short8 sv;
#pragma unroll
    for (int j = 0; j < 8; ++j) {
      int k = g * 8 + j;
      u16 v = 0;
      if (k < 270) {
        int c = k / 9, r9 = k % 9;
        int ky = r9 / 3, kx = r9 % 3;
        v = patch[(c * 10 + py + ky) * 10 + (px + kx)];
      }
      sv[j] = (short)v;
    }
    int off = (p * 320 + g * 8) ^ ((p & 7) << 3);
    *(short8*)(Xt + off) = sv;
  }
  __syncthreads();

  int lane = tid & 63, wave = tid >> 6;
  int lrow = lane & 15, lgrp = lane >> 4;
  int fbase = wave * 64;

  f32x4 acc[4][4];
#pragma unroll
  for (int i = 0; i < 4; ++i)
#pragma unroll
    for (int j = 0; j < 4; ++j) acc[i][j] = (f32x4){0.f, 0.f, 0.f, 0.f};

  const u16* whib = Whi + (fbase + lrow) * 288 + lgrp * 8;
  const u16* wlob = Wlo + (fbase + lrow) * 288 + lgrp * 8;

  for (int ks = 0; ks < 9; ++ks) {
    short8 bfr[4];
#pragma unroll
    for (int pt = 0; pt < 4; ++pt) {
      int p = pt * 16 + lrow;
      int off = (p * 320 + ks * 32 + lgrp * 8) ^ ((p & 7) << 3);
      bfr[pt] = *(const short8*)(Xt + off);
    }
#pragma unroll
    for (int ft = 0; ft < 4; ++ft) {
      short8 ahi = *(const short8*)(whib + ft * 16 * 288 + ks * 32);
      short8 alo = *(const short8*)(wlob + ft * 16 * 288 + ks * 32);
#pragma unroll
      for (int pt = 0; pt < 4; ++pt) {
        acc[ft][pt] = __builtin_amdgcn_mfma_f32_16x16x32_bf16(
            ahi, bfr[pt], acc[ft][pt], 0, 0, 0);
        acc[ft][pt] = __builtin_amdgcn_mfma_f32_16x16x32_bf16(
            alo, bfr[pt], acc[ft][pt], 0, 0, 0);
      }
    }
  }

  // epilogue: threshold >=10, per-position max/argmax over f (first-max)
  __syncthreads();
  float* redv = (float*)lds;            // 256 f32
  int*   redi = (int*)(lds + 512);      // 256 i32

#pragma unroll
  for (int pt = 0; pt < 4; ++pt) {
    float bv = -1.f; int bf = 0;
#pragma unroll
    for (int ft = 0; ft < 4; ++ft)
#pragma unroll
      for (int r = 0; r < 4; ++r) {
        float v = acc[ft][pt][r];
        v = (v >= 10.f) ? v : 0.f;
        int f = fbase + ft * 16 + lgrp * 4 + r;
        if (v > bv) { bv = v; bf = f; }
      }
    {
      float ov = __shfl_xor(bv, 16); int of = __shfl_xor(bf, 16);
      if (ov > bv || (ov == bv && of < bf)) { bv = ov; bf = of; }
      ov = __shfl_xor(bv, 32); of = __shfl_xor(bf, 32);
      if (ov > bv || (ov == bv && of < bf)) { bv = ov; bf = of; }
    }
    if (lgrp == 0) {
      redv[wave * 64 + pt * 16 + lrow] = bv;
      redi[wave * 64 + pt * 16 + lrow] = bf;
    }
  }
  __syncthreads();
  if (tid < 64) {
    float bv = -1.f; int bf = 0x7fffffff;
#pragma unroll
    for (int w = 0; w < 4; ++w) {
      float v = redv[w * 64 + tid]; int f = redi[w * 64 + tid];
      if (v > bv || (v == bv && f < bf)) { bv = v; bf = f; }
    }
    int pos = (y0 + (tid >> 3)) * 80 + x0 + (tid & 7);
    maxv_ws[t * 6400 + pos] = bv;
    argm_ws[t * 6400 + pos] = bf;
  }
}

// ---------------------------------------------------------------------------
__global__ __launch_bounds__(256) void winmap_kernel(
    const float* __restrict__ maxv, const int* __restrict__ argm,
    int* __restrict__ winmap) {
  int pos = blockIdx.x * 256 + threadIdx.x;
  if (pos >= 6400) return;
  int nc = 0;
#pragma unroll
  for (int t = 0; t < T_STEPS; ++t) nc += (maxv[t * 6400 + pos] > 0.f) ? 1 : 0;
  int e = T_STEPS - nc; if (e > 14) e = 14;
  int win = argm[e * 6400 + pos];
  bool gate = maxv[14 * 6400 + pos] > 0.f;
  winmap[pos] = gate ? win : -1;
}

// ---------------------------------------------------------------------------
// exact fp32 recompute of winner-channel potentials (bit-matches reference)
__global__ __launch_bounds__(256) void recompute_kernel(
    const u16* __restrict__ spk_in, const float* __restrict__ w2,
    const int* __restrict__ winmap, float* __restrict__ potwin) {
  int idx = blockIdx.x * 256 + threadIdx.x;   // < 96000
  int pos = idx % 6400, t = idx / 6400;
  int win = winmap[pos];
  float p = 0.f;
  if (win >= 0) {
    int h = pos / 80, w = pos % 80;
    const float* wt = w2 + win * 270;
    const u16* base = spk_in + (size_t)t * 30 * 6724;
    float a = 0.f;
    for (int c = 0; c < 30; ++c) {
#pragma unroll
      for (int ky = 0; ky < 3; ++ky)
#pragma unroll
        for (int kx = 0; kx < 3; ++kx)
          a = fmaf(wt[c * 9 + ky * 3 + kx],
                   bf2f(base[c * 6724 + (h + ky) * 82 + (w + kx)]), a);
    }
    p = (a >= 10.f) ? a : 0.f;
  }
  potwin[idx] = p;
}

// ---------------------------------------------------------------------------
// get_k_winners on compacted entries; wave-shfl reductions (3 syncs/round)
__global__ __launch_bounds__(1024) void winners_kernel(
    const int* __restrict__ winmap, const float* __restrict__ potwin,
    float* __restrict__ out_win) {
  __shared__ float tv[6400];
  __shared__ int   tf[6400];
  __shared__ float wv_s[16];
  __shared__ int   wk_s[16];
  __shared__ int   sh_w[4];
  __shared__ float vmax_s;

  int tid = threadIdx.x;
  int lane = tid & 63, wid = tid >> 6;

  // phase 1: per-position value at first-spike time + global trunc-max
  float localmax = 0.f;
  for (int pos = tid; pos < 6400; pos += 1024) {
    int win = winmap[pos];
    float val = 0.f; int nspk = 0;
    if (win >= 0) {
#pragma unroll
      for (int t = 0; t < T_STEPS; ++t)
        nspk += (potwin[t * 6400 + pos] > 0.f) ? 1 : 0;
      int first = T_STEPS - nspk; if (first > 14) first = 14;
      val = potwin[first * 6400 + pos];
      if (nspk > 0 && val > localmax) localmax = val;
    }
    tv[pos] = val;
    tf[pos] = ((win + 1) << 4) | nspk;
  }
#pragma unroll
  for (int m = 1; m < 64; m <<= 1)
    localmax = fmaxf(localmax, __shfl_xor(localmax, m));
  if (lane == 0) wv_s[wid] = localmax;
  __syncthreads();
  if (tid == 0) {
    float m = 0.f;
#pragma unroll
    for (int w = 0; w < 16; ++w) m = fmaxf(m, wv_s[w]);
    vmax_s = m * (float)T_STEPS;
  }
  __syncthreads();
  float v = vmax_s;

  // phase 2: totals = nspk * (val + v)
  for (int pos = tid; pos < 6400; pos += 1024) {
    int meta = tf[pos];
    int win = (meta >> 4) - 1, nspk = meta & 15;
    tf[pos] = win;
    tv[pos] = (win >= 0) ? (float)nspk * (tv[pos] + v) : 0.f;
  }
  __syncthreads();

  // phase 3: 8 rounds of argmax (value desc, flat-index asc) + suppression
  for (int it = 0; it < 8; ++it) {
    float bv = -1.f; int bk = 0x7fffffff;
    for (int pos = tid; pos < 6400; pos += 1024) {
      float tvv = tv[pos];
      int key = tf[pos] * 6400 + pos;
      if (tvv > bv || (tvv == bv && key < bk)) { bv = tvv; bk = key; }
    }
#pragma unroll
    for (int m = 1; m < 64; m <<= 1) {
      float ov = __shfl_xor(bv, m); int ok = __shfl_xor(bk, m);
      if (ov > bv || (ov == bv && ok < bk)) { bv = ov; bk = ok; }
    }
    if (lane == 0) { wv_s[wid] = bv; wk_s[wid] = bk; }
    __syncthreads();
    if (tid == 0) {
      float mbv = -1.f; int mbk = 0x7fffffff;
#pragma unroll
      for (int w = 0; w < 16; ++w) {
        float ov = wv_s[w]; int ok = wk_s[w];
        if (ov > mbv || (ov == mbv && ok < mbk)) { mbv = ov; mbk = ok; }
      }
      int f = -1, r = -1, c = -1, valid = 0;
      if (mbv != 0.f) {
        f = mbk / 6400; int pos = mbk % 6400;
        r = pos / 80; c = pos % 80;
        valid = 1;
      }
      out_win[it * 3 + 0] = (float)f;
      out_win[it * 3 + 1] = (float)r;
      out_win[it * 3 + 2] = (float)c;
      sh_w[0] = f; sh_w[1] = r; sh_w[2] = c; sh_w[3] = valid;
    }
    __syncthreads();
    if (sh_w[3]) {
      int wf = sh_w[0], wr = sh_w[1], wc = sh_w[2];
      for (int pos = tid; pos < 6400; pos += 1024) {
        int r = pos / 80, c = pos % 80;
        int dr = r - wr; if (dr < 0) dr = -dr;
        int dc = c - wc; if (dc < 0) dc = -dc;
        if (tf[pos] == wf || (dr <= 1 && dc <= 1)) tv[pos] = 0.f;
      }
    }
    __syncthreads();
  }
}

// ---------------------------------------------------------------------------
__global__ __launch_bounds__(256) void scatter_kernel(
    const int* __restrict__ winmap, const float* __restrict__ potwin,
    float* __restrict__ out) {
  int pos = blockIdx.x * 256 + threadIdx.x;
  if (pos >= 6400) return;
  int win = winmap[pos];
  if (win < 0) return;
#pragma unroll
  for (int t = 0; t < T_STEPS; ++t) {
    float p = potwin[t * 6400 + pos];
    int o = (t * 250 + win) * 6400 + pos;
    out[o] = (p > 0.f) ? 1.f : 0.f;
    out[24000000 + o] = p;
  }
}

// ---------------------------------------------------------------------------
extern "C" void kernel_launch(void* const* d_in, const int* in_sizes, int n_in,
                              void* d_out, int out_size, void* d_ws,
                              size_t ws_size, hipStream_t stream) {
  const int*   xin = (const int*)d_in[0];
  const float* w1  = (const float*)d_in[1];
  const float* w2  = (const float*)d_in[2];
  float* out = (float*)d_out;
  char*  ws  = (char*)d_ws;

  u16*   Whi    = (u16*)(ws + WHI_OFF);
  u16*   Wlo    = (u16*)(ws + WLO_OFF);
  u16*   spk_in = (u16*)(ws + SPKIN_OFF);
  float* maxv   = (float*)(ws + MAXV_OFF);
  int*   argm   = (int*)(ws + ARGM_OFF);
  int*   winmap = (int*)(ws + WINMAP_OFF);
  float* potwin = (float*)(ws + POTWIN_OFF);

  hipMemsetAsync(d_out, 0, (size_t)out_size * sizeof(float), stream);
  hipMemsetAsync(spk_in, 0, (size_t)6051600, stream);

  prep_wt_kernel  <<<288,  256, 0, stream>>>(w2, Whi, Wlo);
  conv1_kernel    <<<375,  256, 0, stream>>>(xin, w1, spk_in);
  conv2_kernel    <<<1500, 256, 0, stream>>>(spk_in, Whi, Wlo, maxv, argm);
  winmap_kernel   <<<25,   256, 0, stream>>>(maxv, argm, winmap);
  recompute_kernel<<<375,  256, 0, stream>>>(spk_in, w2, winmap, potwin);
  winners_kernel  <<<1,   1024, 0, stream>>>(winmap, potwin, out + 48000000);
  scatter_kernel  <<<25,   256, 0, stream>>>(winmap, potwin, out);
}

// Round 3
// 192.749 us; speedup vs baseline: 1.9995x; 1.2064x over previous
//
#include <hip/hip_runtime.h>

// ---------------------------------------------------------------------------
// MozafariMNIST2018 SNN forward (training branch, max_layer==2) for MI355X.
//
//  conv1 AND conv2 run on matrix cores with binary bf16 activations.
//  conv2 weights use hi+lo bf16 split (argmax gaps ~0.01 need <1e-3 error);
//  conv1 weights use single bf16 (threshold margin ~25 >> 0.12 max error,
//  and conv1 potentials never reach the output).
//  All output values are recomputed exactly in fp32 for winner channels only.
//  d_out zeroing via custom float4 fill (rocclr fillBuffer was ~1.7 TB/s).
// ---------------------------------------------------------------------------

typedef unsigned short u16;
typedef __attribute__((ext_vector_type(8))) short short8;
typedef __attribute__((ext_vector_type(4))) float f32x4;
typedef __attribute__((ext_vector_type(4))) float float4v;

#define T_STEPS 15

// ws layout (byte offsets), all 16B aligned
#define WHI_OFF     0u         // 256*288 u16 = 147456 B
#define WLO_OFF     147456u    // 147456 B
#define SPKIN_OFF   294912u    // 15*30*82*82 u16 = 6051600 B
#define MAXV_OFF    6346512u   // 96000 f32
#define ARGM_OFF    6730512u   // 96000 i32
#define WINMAP_OFF  7114512u   // 6400 i32
#define POTWIN_OFF  7140112u   // 96000 f32 -> end 7524112

static __device__ __forceinline__ u16 f2bf_rne(float f) {
  unsigned u = __float_as_uint(f);
  unsigned r = u + 0x7FFFu + ((u >> 16) & 1u);
  return (u16)(r >> 16);
}
static __device__ __forceinline__ float bf2f(u16 b) {
  return __uint_as_float(((unsigned)b) << 16);
}

// ---------------------------------------------------------------------------
// grid-stride float4 zero fill (streaming-write bound)
__global__ __launch_bounds__(256) void fill_kernel(float4v* __restrict__ p,
                                                   int n4) {
  int i = blockIdx.x * 256 + threadIdx.x;
  int stride = gridDim.x * 256;
  float4v z = {0.f, 0.f, 0.f, 0.f};
  for (; i < n4; i += stride) p[i] = z;
}

// ---------------------------------------------------------------------------
// w2 [250][270] fp32 -> Whi/Wlo [256][288] bf16 (f,k zero-padded)
__global__ __launch_bounds__(256) void prep_wt_kernel(
    const float* __restrict__ w2, u16* __restrict__ Whi,
    u16* __restrict__ Wlo) {
  int g = blockIdx.x * 256 + threadIdx.x;   // < 73728
  int f = g / 288, k = g % 288;
  u16 h = 0, l = 0;
  if (f < 250 && k < 270) {
    float w = w2[f * 270 + k];
    h = f2bf_rne(w);
    l = f2bf_rne(w - bf2f(h));
  }
  Whi[g] = h;
  Wlo[g] = l;
}

// ---------------------------------------------------------------------------
// conv1 via MFMA: binary bf16 input x bf16 weights. Per block: one t, one
// 16x16 unpooled tile. 4 phases x 4 waves, each wave = 16 pos x 32 f x K160.
// Epilogue: fire(>=15) bits -> LDS -> 2x2 OR pool -> spk_in[t][c][82][82].
__global__ __launch_bounds__(256) void conv1_kernel(
    const int* __restrict__ xin, const float* __restrict__ w1,
    u16* __restrict__ spk_in) {
  __shared__ u16 w1s[32 * 160];           // bf16 weights, padded
  __shared__ u16 patch[6 * 20 * 20];      // bf16 binary input window
  __shared__ unsigned char fires[30 * 256];

  int tid = threadIdx.x;
  int b = blockIdx.x;
  int t = b / 100, tile = b % 100;
  int ty0 = (tile / 10) * 16, tx0 = (tile % 10) * 16;

  for (int idx = tid; idx < 32 * 160; idx += 256) {
    int f = idx / 160, k = idx % 160;
    w1s[idx] = (f < 30 && k < 150) ? f2bf_rne(w1[f * 150 + k]) : (u16)0;
  }
  for (int idx = tid; idx < 2400; idx += 256) {
    int c = idx / 400, rem = idx % 400;
    int r = rem / 20, col = rem % 20;
    int gy = ty0 + r - 2, gx = tx0 + col - 2;
    u16 v = 0;
    if ((unsigned)gy < 160u && (unsigned)gx < 160u)
      v = xin[((t * 6 + c) * 160 + gy) * 160 + gx] ? (u16)0x3F80 : (u16)0;
    patch[idx] = v;
  }
  __syncthreads();

  int lane = tid & 63, wave = tid >> 6;
  int lrow = lane & 15, lgrp = lane >> 4;

  // A fragments (weights) hoisted to registers: [Mtile][Kstep]
  short8 afr[2][5];
#pragma unroll
  for (int m = 0; m < 2; ++m)
#pragma unroll
    for (int ks = 0; ks < 5; ++ks)
      afr[m][ks] =
          *(const short8*)&w1s[(m * 16 + lrow) * 160 + ks * 32 + lgrp * 8];

  // per-lane gather offsets into patch (position-independent part)
  int offs[5][8];
#pragma unroll
  for (int ks = 0; ks < 5; ++ks)
#pragma unroll
    for (int j = 0; j < 8; ++j) {
      int k = ks * 32 + lgrp * 8 + j;
      if (k < 150) {
        int c = k / 25, r = k % 25, ky = r / 5, kx = r % 5;
        offs[ks][j] = c * 400 + ky * 20 + kx;
      } else {
        offs[ks][j] = -1;
      }
    }

  for (int ph = 0; ph < 4; ++ph) {
    int rrow = ph * 4 + wave;           // local unpooled y (0..15)
    int pbase = rrow * 20 + lrow;       // + (ky*20+kx) + c*400 via offs
    short8 bfr[5];
#pragma unroll
    for (int ks = 0; ks < 5; ++ks)
#pragma unroll
      for (int j = 0; j < 8; ++j) {
        int o = offs[ks][j];
        bfr[ks][j] = (o >= 0) ? (short)patch[o + pbase] : (short)0;
      }
    f32x4 acc0 = {0.f, 0.f, 0.f, 0.f}, acc1 = {0.f, 0.f, 0.f, 0.f};
#pragma unroll
    for (int ks = 0; ks < 5; ++ks) {
      acc0 = __builtin_amdgcn_mfma_f32_16x16x32_bf16(afr[0][ks], bfr[ks],
                                                     acc0, 0, 0, 0);
      acc1 = __builtin_amdgcn_mfma_f32_16x16x32_bf16(afr[1][ks], bfr[ks],
                                                     acc1, 0, 0, 0);
    }
#pragma unroll
    for (int r = 0; r < 4; ++r) {
      int f0 = lgrp * 4 + r;
      fires[f0 * 256 + rrow * 16 + lrow] = (acc0[r] >= 15.f);
      int f1 = 16 + lgrp * 4 + r;
      if (f1 < 30) fires[f1 * 256 + rrow * 16 + lrow] = (acc1[r] >= 15.f);
    }
  }
  __syncthreads();

  // 2x2 OR pooling -> spk_in (padded 82x82)
  int pby0 = (ty0 >> 1) + 1, pbx0 = (tx0 >> 1) + 1;
  for (int idx = tid; idx < 30 * 64; idx += 256) {
    int f = idx >> 6, pp = idx & 63;
    int py = pp >> 3, px = pp & 7;
    const unsigned char* fb = &fires[f * 256 + py * 32 + px * 2];
    int v = fb[0] | fb[1] | fb[16] | fb[17];
    spk_in[((t * 30 + f) * 82 + pby0 + py) * 82 + pbx0 + px] =
        v ? (u16)0x3F80 : (u16)0;
  }
}

// ---------------------------------------------------------------------------
// conv2 implicit-GEMM MFMA. grid 15*100, block 256 (4 waves).
// Block tile: 256 f (padded) x 64 pos (8x8), K = 288 (9 MFMA steps), hi+lo.
// Emits per (t,h,w): max_f / argmax_f of thresholded potentials.
__global__ __launch_bounds__(256) void conv2_kernel(
    const u16* __restrict__ spk_in, const u16* __restrict__ Whi,
    const u16* __restrict__ Wlo, float* __restrict__ maxv_ws,
    int* __restrict__ argm_ws) {
  __shared__ __align__(16) u16 lds[64 * 320 + 3008];  // Xt (swizzled) + patch
  u16* Xt = lds;
  u16* patch = lds + 20480;

  int tid = threadIdx.x;
  int b = blockIdx.x;
  int t = b / 100, tile = b % 100;
  int y0 = (tile / 10) * 8, x0 = (tile % 10) * 8;

  const u16* sb = spk_in + (size_t)t * 30 * 6724;
  for (int idx = tid; idx < 3000; idx += 256) {
    int c = idx / 100, rem = idx % 100;
    int dy = rem / 10, dx = rem % 10;
    patch[idx] = sb[c * 6724 + (y0 + dy) * 82 + (x0 + dx)];
  }
  __syncthreads();

  for (int task = tid; task < 2304; task += 256) {
    int p = task / 36, g = task % 36;
    int py = p >> 3, px = p & 7;
    short8 sv;
#pragma unroll
    for (int j = 0; j < 8; ++j) {
      int k = g * 8 + j;
      u16 v = 0;
      if (k < 270) {
        int c = k / 9, r9 = k % 9;
        int ky = r9 / 3, kx = r9 % 3;
        v = patch[(c * 10 + py + ky) * 10 + (px + kx)];
      }
      sv[j] = (short)v;
    }
    int off = (p * 320 + g * 8) ^ ((p & 7) << 3);
    *(short8*)(Xt + off) = sv;
  }
  __syncthreads();

  int lane = tid & 63, wave = tid >> 6;
  int lrow = lane & 15, lgrp = lane >> 4;
  int fbase = wave * 64;

  f32x4 acc[4][4];
#pragma unroll
  for (int i = 0; i < 4; ++i)
#pragma unroll
    for (int j = 0; j < 4; ++j) acc[i][j] = (f32x4){0.f, 0.f, 0.f, 0.f};

  const u16* whib = Whi + (fbase + lrow) * 288 + lgrp * 8;
  const u16* wlob = Wlo + (fbase + lrow) * 288 + lgrp * 8;

  for (int ks = 0; ks < 9; ++ks) {
    short8 bfr[4];
#pragma unroll
    for (int pt = 0; pt < 4; ++pt) {
      int p = pt * 16 + lrow;
      int off = (p * 320 + ks * 32 + lgrp * 8) ^ ((p & 7) << 3);
      bfr[pt] = *(const short8*)(Xt + off);
    }
#pragma unroll
    for (int ft = 0; ft < 4; ++ft) {
      short8 ahi = *(const short8*)(whib + ft * 16 * 288 + ks * 32);
      short8 alo = *(const short8*)(wlob + ft * 16 * 288 + ks * 32);
#pragma unroll
      for (int pt = 0; pt < 4; ++pt) {
        acc[ft][pt] = __builtin_amdgcn_mfma_f32_16x16x32_bf16(
            ahi, bfr[pt], acc[ft][pt], 0, 0, 0);
        acc[ft][pt] = __builtin_amdgcn_mfma_f32_16x16x32_bf16(
            alo, bfr[pt], acc[ft][pt], 0, 0, 0);
      }
    }
  }

  __syncthreads();
  float* redv = (float*)lds;
  int*   redi = (int*)(lds + 512);

#pragma unroll
  for (int pt = 0; pt < 4; ++pt) {
    float bv = -1.f; int bf = 0;
#pragma unroll
    for (int ft = 0; ft < 4; ++ft)
#pragma unroll
      for (int r = 0; r < 4; ++r) {
        float v = acc[ft][pt][r];
        v = (v >= 10.f) ? v : 0.f;
        int f = fbase + ft * 16 + lgrp * 4 + r;
        if (v > bv) { bv = v; bf = f; }
      }
    {
      float ov = __shfl_xor(bv, 16); int of = __shfl_xor(bf, 16);
      if (ov > bv || (ov == bv && of < bf)) { bv = ov; bf = of; }
      ov = __shfl_xor(bv, 32); of = __shfl_xor(bf, 32);
      if (ov > bv || (ov == bv && of < bf)) { bv = ov; bf = of; }
    }
    if (lgrp == 0) {
      redv[wave * 64 + pt * 16 + lrow] = bv;
      redi[wave * 64 + pt * 16 + lrow] = bf;
    }
  }
  __syncthreads();
  if (tid < 64) {
    float bv = -1.f; int bf = 0x7fffffff;
#pragma unroll
    for (int w = 0; w < 4; ++w) {
      float v = redv[w * 64 + tid]; int f = redi[w * 64 + tid];
      if (v > bv || (v == bv && f < bf)) { bv = v; bf = f; }
    }
    int pos = (y0 + (tid >> 3)) * 80 + x0 + (tid & 7);
    maxv_ws[t * 6400 + pos] = bv;
    argm_ws[t * 6400 + pos] = bf;
  }
}

// ---------------------------------------------------------------------------
__global__ __launch_bounds__(256) void winmap_kernel(
    const float* __restrict__ maxv, const int* __restrict__ argm,
    int* __restrict__ winmap) {
  int pos = blockIdx.x * 256 + threadIdx.x;
  if (pos >= 6400) return;
  int nc = 0;
#pragma unroll
  for (int t = 0; t < T_STEPS; ++t) nc += (maxv[t * 6400 + pos] > 0.f) ? 1 : 0;
  int e = T_STEPS - nc; if (e > 14) e = 14;
  int win = argm[e * 6400 + pos];
  bool gate = maxv[14 * 6400 + pos] > 0.f;
  winmap[pos] = gate ? win : -1;
}

// ---------------------------------------------------------------------------
__global__ __launch_bounds__(256) void recompute_kernel(
    const u16* __restrict__ spk_in, const float* __restrict__ w2,
    const int* __restrict__ winmap, float* __restrict__ potwin) {
  int idx = blockIdx.x * 256 + threadIdx.x;   // < 96000
  int pos = idx % 6400, t = idx / 6400;
  int win = winmap[pos];
  float p = 0.f;
  if (win >= 0) {
    int h = pos / 80, w = pos % 80;
    const float* wt = w2 + win * 270;
    const u16* base = spk_in + (size_t)t * 30 * 6724;
    float a = 0.f;
    for (int c = 0; c < 30; ++c) {
#pragma unroll
      for (int ky = 0; ky < 3; ++ky)
#pragma unroll
        for (int kx = 0; kx < 3; ++kx)
          a = fmaf(wt[c * 9 + ky * 3 + kx],
                   bf2f(base[c * 6724 + (h + ky) * 82 + (w + kx)]), a);
    }
    p = (a >= 10.f) ? a : 0.f;
  }
  potwin[idx] = p;
}

// ---------------------------------------------------------------------------
__global__ __launch_bounds__(1024) void winners_kernel(
    const int* __restrict__ winmap, const float* __restrict__ potwin,
    float* __restrict__ out_win) {
  __shared__ float tv[6400];
  __shared__ int   tf[6400];
  __shared__ float wv_s[16];
  __shared__ int   wk_s[16];
  __shared__ int   sh_w[4];
  __shared__ float vmax_s;

  int tid = threadIdx.x;
  int lane = tid & 63, wid = tid >> 6;

  float localmax = 0.f;
  for (int pos = tid; pos < 6400; pos += 1024) {
    int win = winmap[pos];
    float val = 0.f; int nspk = 0;
    if (win >= 0) {
#pragma unroll
      for (int t = 0; t < T_STEPS; ++t)
        nspk += (potwin[t * 6400 + pos] > 0.f) ? 1 : 0;
      int first = T_STEPS - nspk; if (first > 14) first = 14;
      val = potwin[first * 6400 + pos];
      if (nspk > 0 && val > localmax) localmax = val;
    }
    tv[pos] = val;
    tf[pos] = ((win + 1) << 4) | nspk;
  }
#pragma unroll
  for (int m = 1; m < 64; m <<= 1)
    localmax = fmaxf(localmax, __shfl_xor(localmax, m));
  if (lane == 0) wv_s[wid] = localmax;
  __syncthreads();
  if (tid == 0) {
    float m = 0.f;
#pragma unroll
    for (int w = 0; w < 16; ++w) m = fmaxf(m, wv_s[w]);
    vmax_s = m * (float)T_STEPS;
  }
  __syncthreads();
  float v = vmax_s;

  for (int pos = tid; pos < 6400; pos += 1024) {
    int meta = tf[pos];
    int win = (meta >> 4) - 1, nspk = meta & 15;
    tf[pos] = win;
    tv[pos] = (win >= 0) ? (float)nspk * (tv[pos] + v) : 0.f;
  }
  __syncthreads();

  for (int it = 0; it < 8; ++it) {
    float bv = -1.f; int bk = 0x7fffffff;
    for (int pos = tid; pos < 6400; pos += 1024) {
      float tvv = tv[pos];
      int key = tf[pos] * 6400 + pos;
      if (tvv > bv || (tvv == bv && key < bk)) { bv = tvv; bk = key; }
    }
#pragma unroll
    for (int m = 1; m < 64; m <<= 1) {
      float ov = __shfl_xor(bv, m); int ok = __shfl_xor(bk, m);
      if (ov > bv || (ov == bv && ok < bk)) { bv = ov; bk = ok; }
    }
    if (lane == 0) { wv_s[wid] = bv; wk_s[wid] = bk; }
    __syncthreads();
    if (tid == 0) {
      float mbv = -1.f; int mbk = 0x7fffffff;
#pragma unroll
      for (int w = 0; w < 16; ++w) {
        float ov = wv_s[w]; int ok = wk_s[w];
        if (ov > mbv || (ov == mbv && ok < mbk)) { mbv = ov; mbk = ok; }
      }
      int f = -1, r = -1, c = -1, valid = 0;
      if (mbv != 0.f) {
        f = mbk / 6400; int pos = mbk % 6400;
        r = pos / 80; c = pos % 80;
        valid = 1;
      }
      out_win[it * 3 + 0] = (float)f;
      out_win[it * 3 + 1] = (float)r;
      out_win[it * 3 + 2] = (float)c;
      sh_w[0] = f; sh_w[1] = r; sh_w[2] = c; sh_w[3] = valid;
    }
    __syncthreads();
    if (sh_w[3]) {
      int wf = sh_w[0], wr = sh_w[1], wc = sh_w[2];
      for (int pos = tid; pos < 6400; pos += 1024) {
        int r = pos / 80, c = pos % 80;
        int dr = r - wr; if (dr < 0) dr = -dr;
        int dc = c - wc; if (dc < 0) dc = -dc;
        if (tf[pos] == wf || (dr <= 1 && dc <= 1)) tv[pos] = 0.f;
      }
    }
    __syncthreads();
  }
}

// ---------------------------------------------------------------------------
__global__ __launch_bounds__(256) void scatter_kernel(
    const int* __restrict__ winmap, const float* __restrict__ potwin,
    float* __restrict__ out) {
  int pos = blockIdx.x * 256 + threadIdx.x;
  if (pos >= 6400) return;
  int win = winmap[pos];
  if (win < 0) return;
#pragma unroll
  for (int t = 0; t < T_STEPS; ++t) {
    float p = potwin[t * 6400 + pos];
    int o = (t * 250 + win) * 6400 + pos;
    out[o] = (p > 0.f) ? 1.f : 0.f;
    out[24000000 + o] = p;
  }
}

// ---------------------------------------------------------------------------
extern "C" void kernel_launch(void* const* d_in, const int* in_sizes, int n_in,
                              void* d_out, int out_size, void* d_ws,
                              size_t ws_size, hipStream_t stream) {
  const int*   xin = (const int*)d_in[0];
  const float* w1  = (const float*)d_in[1];
  const float* w2  = (const float*)d_in[2];
  float* out = (float*)d_out;
  char*  ws  = (char*)d_ws;

  u16*   Whi    = (u16*)(ws + WHI_OFF);
  u16*   Wlo    = (u16*)(ws + WLO_OFF);
  u16*   spk_in = (u16*)(ws + SPKIN_OFF);
  float* maxv   = (float*)(ws + MAXV_OFF);
  int*   argm   = (int*)(ws + ARGM_OFF);
  int*   winmap = (int*)(ws + WINMAP_OFF);
  float* potwin = (float*)(ws + POTWIN_OFF);

  // zero d_out (48,000,024 f32 = 12,000,006 float4) and spk_in (378,225 f4)
  fill_kernel<<<2048, 256, 0, stream>>>((float4v*)d_out, 12000006);
  fill_kernel<<<740,  256, 0, stream>>>((float4v*)spk_in, 378225);

  prep_wt_kernel  <<<288,  256, 0, stream>>>(w2, Whi, Wlo);
  conv1_kernel    <<<1500, 256, 0, stream>>>(xin, w1, spk_in);
  conv2_kernel    <<<1500, 256, 0, stream>>>(spk_in, Whi, Wlo, maxv, argm);
  winmap_kernel   <<<25,   256, 0, stream>>>(maxv, argm, winmap);
  recompute_kernel<<<375,  256, 0, stream>>>(spk_in, w2, winmap, potwin);
  winners_kernel  <<<1,   1024, 0, stream>>>(winmap, potwin, out + 48000000);
  scatter_kernel  <<<25,   256, 0, stream>>>(winmap, potwin, out);
}

// Round 4
// 192.133 us; speedup vs baseline: 2.0059x; 1.0032x over previous
//
#include <hip/hip_runtime.h>

// ---------------------------------------------------------------------------
// MozafariMNIST2018 SNN forward (training branch, max_layer==2) for MI355X.
//
//  conv1 AND conv2 on matrix cores (binary bf16 activations; conv2 weights
//  hi+lo bf16-split so argmax decisions match fp32; conv1 single bf16 since
//  threshold margin ~25 >> max error). All output VALUES come from exact
//  fp32 recompute of winner channels only -> absmax 0.
//  conv2: 2 t per block (halves L2 weight traffic), K phase-split 160+128.
//  recompute: LDS-staged input patch per (t, 16x16 pos) tile.
// ---------------------------------------------------------------------------

typedef unsigned short u16;
typedef __attribute__((ext_vector_type(8))) short short8;
typedef __attribute__((ext_vector_type(4))) float f32x4;
typedef __attribute__((ext_vector_type(4))) float float4v;

#define T_STEPS 15

// ws layout (byte offsets), all 16B aligned
#define WHI_OFF     0u         // 256*288 u16 = 147456 B
#define WLO_OFF     147456u    // 147456 B
#define SPKIN_OFF   294912u    // 15*30*82*82 u16 = 6051600 B
#define MAXV_OFF    6346512u   // 96000 f32
#define ARGM_OFF    6730512u   // 96000 i32
#define WINMAP_OFF  7114512u   // 6400 i32
#define POTWIN_OFF  7140112u   // 96000 f32 -> end 7524112

static __device__ __forceinline__ u16 f2bf_rne(float f) {
  unsigned u = __float_as_uint(f);
  unsigned r = u + 0x7FFFu + ((u >> 16) & 1u);
  return (u16)(r >> 16);
}
static __device__ __forceinline__ float bf2f(u16 b) {
  return __uint_as_float(((unsigned)b) << 16);
}

// ---------------------------------------------------------------------------
__global__ __launch_bounds__(256) void fill_kernel(float4v* __restrict__ p,
                                                   int n4) {
  int i = blockIdx.x * 256 + threadIdx.x;
  int stride = gridDim.x * 256;
  float4v z = {0.f, 0.f, 0.f, 0.f};
  for (; i < n4; i += stride) p[i] = z;
}

// ---------------------------------------------------------------------------
__global__ __launch_bounds__(256) void prep_wt_kernel(
    const float* __restrict__ w2, u16* __restrict__ Whi,
    u16* __restrict__ Wlo) {
  int g = blockIdx.x * 256 + threadIdx.x;   // < 73728
  int f = g / 288, k = g % 288;
  u16 h = 0, l = 0;
  if (f < 250 && k < 270) {
    float w = w2[f * 270 + k];
    h = f2bf_rne(w);
    l = f2bf_rne(w - bf2f(h));
  }
  Whi[g] = h;
  Wlo[g] = l;
}

// ---------------------------------------------------------------------------
// conv1 via MFMA: binary bf16 input x bf16 weights. Per block: one t, one
// 16x16 unpooled tile. 4 phases x 4 waves, each wave = 16 pos x 32 f x K160.
// Epilogue: fire(>=15) bits -> LDS -> 2x2 OR pool -> spk_in[t][c][82][82].
__global__ __launch_bounds__(256) void conv1_kernel(
    const int* __restrict__ xin, const float* __restrict__ w1,
    u16* __restrict__ spk_in) {
  __shared__ u16 w1s[32 * 160];           // bf16 weights, padded
  __shared__ u16 patch[6 * 20 * 20 + 320];  // + zero pad region for gather
  __shared__ unsigned char fires[30 * 256];

  int tid = threadIdx.x;
  int b = blockIdx.x;
  int t = b / 100, tile = b % 100;
  int ty0 = (tile / 10) * 16, tx0 = (tile % 10) * 16;

  for (int idx = tid; idx < 32 * 160; idx += 256) {
    int f = idx / 160, k = idx % 160;
    w1s[idx] = (f < 30 && k < 150) ? f2bf_rne(w1[f * 150 + k]) : (u16)0;
  }
  for (int idx = tid; idx < 2720; idx += 256) {
    u16 v = 0;
    if (idx < 2400) {
      int c = idx / 400, rem = idx % 400;
      int r = rem / 20, col = rem % 20;
      int gy = ty0 + r - 2, gx = tx0 + col - 2;
      if ((unsigned)gy < 160u && (unsigned)gx < 160u)
        v = xin[((t * 6 + c) * 160 + gy) * 160 + gx] ? (u16)0x3F80 : (u16)0;
    }
    patch[idx] = v;
  }
  __syncthreads();

  int lane = tid & 63, wave = tid >> 6;
  int lrow = lane & 15, lgrp = lane >> 4;

  short8 afr[2][5];
#pragma unroll
  for (int m = 0; m < 2; ++m)
#pragma unroll
    for (int ks = 0; ks < 5; ++ks)
      afr[m][ks] =
          *(const short8*)&w1s[(m * 16 + lrow) * 160 + ks * 32 + lgrp * 8];

  // per-lane gather offsets (k >= 150 -> zeroed pad region at 2400)
  int offs[5][8];
#pragma unroll
  for (int ks = 0; ks < 5; ++ks)
#pragma unroll
    for (int j = 0; j < 8; ++j) {
      int k = ks * 32 + lgrp * 8 + j;
      if (k < 150) {
        int c = k / 25, r = k % 25, ky = r / 5, kx = r % 5;
        offs[ks][j] = c * 400 + ky * 20 + kx;
      } else {
        offs[ks][j] = 2400;
      }
    }

  for (int ph = 0; ph < 4; ++ph) {
    int rrow = ph * 4 + wave;
    int pbase = rrow * 20 + lrow;
    short8 bfr[5];
#pragma unroll
    for (int ks = 0; ks < 5; ++ks)
#pragma unroll
      for (int j = 0; j < 8; ++j)
        bfr[ks][j] = (short)patch[offs[ks][j] + pbase];
    f32x4 acc0 = {0.f, 0.f, 0.f, 0.f}, acc1 = {0.f, 0.f, 0.f, 0.f};
#pragma unroll
    for (int ks = 0; ks < 5; ++ks) {
      acc0 = __builtin_amdgcn_mfma_f32_16x16x32_bf16(afr[0][ks], bfr[ks],
                                                     acc0, 0, 0, 0);
      acc1 = __builtin_amdgcn_mfma_f32_16x16x32_bf16(afr[1][ks], bfr[ks],
                                                     acc1, 0, 0, 0);
    }
#pragma unroll
    for (int r = 0; r < 4; ++r) {
      int f0 = lgrp * 4 + r;
      fires[f0 * 256 + rrow * 16 + lrow] = (acc0[r] >= 15.f);
      int f1 = 16 + lgrp * 4 + r;
      if (f1 < 30) fires[f1 * 256 + rrow * 16 + lrow] = (acc1[r] >= 15.f);
    }
  }
  __syncthreads();

  int pby0 = (ty0 >> 1) + 1, pbx0 = (tx0 >> 1) + 1;
  for (int idx = tid; idx < 30 * 64; idx += 256) {
    int f = idx >> 6, pp = idx & 63;
    int py = pp >> 3, px = pp & 7;
    const unsigned char* fb = &fires[f * 256 + py * 32 + px * 2];
    int v = fb[0] | fb[1] | fb[16] | fb[17];
    spk_in[((t * 30 + f) * 82 + pby0 + py) * 82 + pbx0 + px] =
        v ? (u16)0x3F80 : (u16)0;
  }
}

// ---------------------------------------------------------------------------
// conv2 implicit-GEMM MFMA, 2 time-steps per block.
// grid 8*100, block 512 (8 waves; wave = 32 f). Tile: 256 f x 64 pos x 2 t.
// K split in 2 phases (160 + 128); weights held in regs across both t.
// Emits per (t,h,w): max_f / argmax_f of thresholded potentials.
__global__ __launch_bounds__(512) void conv2_kernel(
    const u16* __restrict__ spk_in, const u16* __restrict__ Whi,
    const u16* __restrict__ Wlo, float* __restrict__ maxv_ws,
    int* __restrict__ argm_ws) {
  __shared__ __align__(16) u16 lds[2 * 64 * 192 + 2 * 3000];  // Xt + patch
  u16* Xt = lds;                    // [t][64 pos][192 K-stride, swizzled]
  u16* patch = lds + 24576;         // [t][30 c][10][10]

  int tid = threadIdx.x;
  int b = blockIdx.x;
  int tp = b / 100, tile = b % 100;
  int t0 = tp * 2;
  bool has_t1 = (t0 + 1) < T_STEPS;
  int y0 = (tile / 10) * 8, x0 = (tile % 10) * 8;

  // stage raw patches for both t (t1==15 reads spill into maxv region: unused)
  for (int idx = tid; idx < 6000; idx += 512) {
    int tt = idx / 3000, rem = idx % 3000;
    int c = rem / 100, r2 = rem % 100;
    int dy = r2 / 10, dx = r2 % 10;
    patch[idx] =
        spk_in[((size_t)(t0 + tt) * 30 + c) * 6724 + (y0 + dy) * 82 + (x0 + dx)];
  }

  int lane = tid & 63, wave = tid >> 6;
  int lrow = lane & 15, lgrp = lane >> 4;

  f32x4 acc[2][2][4];   // [t][ft][pt]
#pragma unroll
  for (int tt = 0; tt < 2; ++tt)
#pragma unroll
    for (int i = 0; i < 2; ++i)
#pragma unroll
      for (int j = 0; j < 4; ++j) acc[tt][i][j] = (f32x4){0.f, 0.f, 0.f, 0.f};

  int xorr = (lrow & 7) << 3;

  for (int ph = 0; ph < 2; ++ph) {
    int nks = ph ? 4 : 5;
    int kbase = ph ? 160 : 0;
    int ng = nks * 4;               // 8-groups per pos this phase
    __syncthreads();                // patch ready / prev-phase Xt reads done
    int ntask = 2 * 64 * ng;
    for (int task = tid; task < ntask; task += 512) {
      int tt = task / (64 * ng), rem = task % (64 * ng);
      int p = rem / ng, g = rem % ng;
      int py = p >> 3, px = p & 7;
      short8 sv;
#pragma unroll
      for (int j = 0; j < 8; ++j) {
        int k = kbase + g * 8 + j;
        u16 v = 0;
        if (k < 270) {
          int c = k / 9, r9 = k % 9;
          int ky = r9 / 3, kx = r9 % 3;
          v = patch[tt * 3000 + c * 100 + (py + ky) * 10 + (px + kx)];
        }
        sv[j] = (short)v;
      }
      int s = (p * 192 + g * 8) ^ ((p & 7) << 3);
      *(short8*)(Xt + tt * 12288 + s) = sv;
    }
    __syncthreads();

    const u16* wh = Whi + (wave * 32 + lrow) * 288 + kbase + lgrp * 8;
    const u16* wl = Wlo + (wave * 32 + lrow) * 288 + kbase + lgrp * 8;
    for (int ks = 0; ks < nks; ++ks) {
      short8 ahi[2], alo[2];
#pragma unroll
      for (int ft = 0; ft < 2; ++ft) {
        ahi[ft] = *(const short8*)(wh + ft * 16 * 288 + ks * 32);
        alo[ft] = *(const short8*)(wl + ft * 16 * 288 + ks * 32);
      }
#pragma unroll
      for (int tt = 0; tt < 2; ++tt) {
        short8 bfr[4];
#pragma unroll
        for (int pt = 0; pt < 4; ++pt) {
          int s = ((pt * 16 + lrow) * 192 + ks * 32 + lgrp * 8) ^ xorr;
          bfr[pt] = *(const short8*)(Xt + tt * 12288 + s);
        }
#pragma unroll
        for (int ft = 0; ft < 2; ++ft)
#pragma unroll
          for (int pt = 0; pt < 4; ++pt) {
            acc[tt][ft][pt] = __builtin_amdgcn_mfma_f32_16x16x32_bf16(
                ahi[ft], bfr[pt], acc[tt][ft][pt], 0, 0, 0);
            acc[tt][ft][pt] = __builtin_amdgcn_mfma_f32_16x16x32_bf16(
                alo[ft], bfr[pt], acc[tt][ft][pt], 0, 0, 0);
          }
      }
    }
  }

  // epilogue: threshold >=10, per-pos max/argmax over f (first-max), per t
  float* redv = (float*)lds;              // [64 pos][9]
  int*   redi = (int*)lds + 640;          // [64 pos][9]
  for (int tt = 0; tt < 2; ++tt) {
    __syncthreads();
#pragma unroll
    for (int pt = 0; pt < 4; ++pt) {
      float bv = -1.f; int bf = 0;
#pragma unroll
      for (int ft = 0; ft < 2; ++ft)
#pragma unroll
        for (int r = 0; r < 4; ++r) {
          float v = acc[tt][ft][pt][r];
          v = (v >= 10.f) ? v : 0.f;
          int f = wave * 32 + ft * 16 + lgrp * 4 + r;
          if (v > bv) { bv = v; bf = f; }
        }
      {
        float ov = __shfl_xor(bv, 16); int of = __shfl_xor(bf, 16);
        if (ov > bv || (ov == bv && of < bf)) { bv = ov; bf = of; }
        ov = __shfl_xor(bv, 32); of = __shfl_xor(bf, 32);
        if (ov > bv || (ov == bv && of < bf)) { bv = ov; bf = of; }
      }
      if (lgrp == 0) {
        int p = pt * 16 + lrow;
        redv[p * 9 + wave] = bv;
        redi[p * 9 + wave] = bf;
      }
    }
    __syncthreads();
    if (tid < 64 && (tt == 0 || has_t1)) {
      float bv = -1.f; int bf = 0x7fffffff;
#pragma unroll
      for (int w = 0; w < 8; ++w) {     // wave ascending = f ascending
        float v = redv[tid * 9 + w]; int f = redi[tid * 9 + w];
        if (v > bv || (v == bv && f < bf)) { bv = v; bf = f; }
      }
      int pos = (y0 + (tid >> 3)) * 80 + x0 + (tid & 7);
      maxv_ws[(t0 + tt) * 6400 + pos] = bv;
      argm_ws[(t0 + tt) * 6400 + pos] = bf;
    }
  }
}

// ---------------------------------------------------------------------------
__global__ __launch_bounds__(256) void winmap_kernel(
    const float* __restrict__ maxv, const int* __restrict__ argm,
    int* __restrict__ winmap) {
  int pos = blockIdx.x * 256 + threadIdx.x;
  if (pos >= 6400) return;
  int nc = 0;
#pragma unroll
  for (int t = 0; t < T_STEPS; ++t) nc += (maxv[t * 6400 + pos] > 0.f) ? 1 : 0;
  int e = T_STEPS - nc; if (e > 14) e = 14;
  int win = argm[e * 6400 + pos];
  bool gate = maxv[14 * 6400 + pos] > 0.f;
  winmap[pos] = gate ? win : -1;
}

// ---------------------------------------------------------------------------
// exact fp32 recompute of winner-channel potentials, LDS-staged input patch.
// grid 15*25 (one t, 16x16 pos tile), block 256 (one thread per pos).
__global__ __launch_bounds__(256) void recompute_kernel(
    const u16* __restrict__ spk_in, const float* __restrict__ w2,
    const int* __restrict__ winmap, float* __restrict__ potwin) {
  __shared__ u16 patch[30 * 18 * 18];     // [c][dy][dx]

  int tid = threadIdx.x;
  int b = blockIdx.x;
  int t = b / 25, tile = b % 25;
  int ty0 = (tile / 5) * 16, tx0 = (tile % 5) * 16;

  const u16* base = spk_in + (size_t)t * 30 * 6724;
  for (int idx = tid; idx < 9720; idx += 256) {
    int c = idx / 324, rem = idx % 324;
    int dy = rem / 18, dx = rem % 18;
    patch[idx] = base[c * 6724 + (ty0 + dy) * 82 + (tx0 + dx)];
  }
  __syncthreads();

  int py = tid >> 4, px = tid & 15;
  int pos = (ty0 + py) * 80 + tx0 + px;
  int win = winmap[pos];
  float p = 0.f;
  if (win >= 0) {
    const float* wt = w2 + win * 270;
    float a = 0.f;
    for (int c = 0; c < 30; ++c) {        // same accumulation order as before
#pragma unroll
      for (int ky = 0; ky < 3; ++ky)
#pragma unroll
        for (int kx = 0; kx < 3; ++kx)
          a = fmaf(wt[c * 9 + ky * 3 + kx],
                   bf2f(patch[c * 324 + (py + ky) * 18 + (px + kx)]), a);
    }
    p = (a >= 10.f) ? a : 0.f;
  }
  potwin[t * 6400 + pos] = p;
}

// ---------------------------------------------------------------------------
__global__ __launch_bounds__(1024) void winners_kernel(
    const int* __restrict__ winmap, const float* __restrict__ potwin,
    float* __restrict__ out_win) {
  __shared__ float tv[6400];
  __shared__ int   tf[6400];
  __shared__ float wv_s[16];
  __shared__ int   wk_s[16];
  __shared__ int   sh_w[4];
  __shared__ float vmax_s;

  int tid = threadIdx.x;
  int lane = tid & 63, wid = tid >> 6;

  float localmax = 0.f;
  for (int pos = tid; pos < 6400; pos += 1024) {
    int win = winmap[pos];
    float val = 0.f; int nspk = 0;
    if (win >= 0) {
#pragma unroll
      for (int t = 0; t < T_STEPS; ++t)
        nspk += (potwin[t * 6400 + pos] > 0.f) ? 1 : 0;
      int first = T_STEPS - nspk; if (first > 14) first = 14;
      val = potwin[first * 6400 + pos];
      if (nspk > 0 && val > localmax) localmax = val;
    }
    tv[pos] = val;
    tf[pos] = ((win + 1) << 4) | nspk;
  }
#pragma unroll
  for (int m = 1; m < 64; m <<= 1)
    localmax = fmaxf(localmax, __shfl_xor(localmax, m));
  if (lane == 0) wv_s[wid] = localmax;
  __syncthreads();
  if (tid == 0) {
    float m = 0.f;
#pragma unroll
    for (int w = 0; w < 16; ++w) m = fmaxf(m, wv_s[w]);
    vmax_s = m * (float)T_STEPS;
  }
  __syncthreads();
  float v = vmax_s;

  for (int pos = tid; pos < 6400; pos += 1024) {
    int meta = tf[pos];
    int win = (meta >> 4) - 1, nspk = meta & 15;
    tf[pos] = win;
    tv[pos] = (win >= 0) ? (float)nspk * (tv[pos] + v) : 0.f;
  }
  __syncthreads();

  for (int it = 0; it < 8; ++it) {
    float bv = -1.f; int bk = 0x7fffffff;
    for (int pos = tid; pos < 6400; pos += 1024) {
      float tvv = tv[pos];
      int key = tf[pos] * 6400 + pos;
      if (tvv > bv || (tvv == bv && key < bk)) { bv = tvv; bk = key; }
    }
#pragma unroll
    for (int m = 1; m < 64; m <<= 1) {
      float ov = __shfl_xor(bv, m); int ok = __shfl_xor(bk, m);
      if (ov > bv || (ov == bv && ok < bk)) { bv = ov; bk = ok; }
    }
    if (lane == 0) { wv_s[wid] = bv; wk_s[wid] = bk; }
    __syncthreads();
    if (tid == 0) {
      float mbv = -1.f; int mbk = 0x7fffffff;
#pragma unroll
      for (int w = 0; w < 16; ++w) {
        float ov = wv_s[w]; int ok = wk_s[w];
        if (ov > mbv || (ov == mbv && ok < mbk)) { mbv = ov; mbk = ok; }
      }
      int f = -1, r = -1, c = -1, valid = 0;
      if (mbv != 0.f) {
        f = mbk / 6400; int pos = mbk % 6400;
        r = pos / 80; c = pos % 80;
        valid = 1;
      }
      out_win[it * 3 + 0] = (float)f;
      out_win[it * 3 + 1] = (float)r;
      out_win[it * 3 + 2] = (float)c;
      sh_w[0] = f; sh_w[1] = r; sh_w[2] = c; sh_w[3] = valid;
    }
    __syncthreads();
    if (sh_w[3]) {
      int wf = sh_w[0], wr = sh_w[1], wc = sh_w[2];
      for (int pos = tid; pos < 6400; pos += 1024) {
        int r = pos / 80, c = pos % 80;
        int dr = r - wr; if (dr < 0) dr = -dr;
        int dc = c - wc; if (dc < 0) dc = -dc;
        if (tf[pos] == wf || (dr <= 1 && dc <= 1)) tv[pos] = 0.f;
      }
    }
    __syncthreads();
  }
}

// ---------------------------------------------------------------------------
__global__ __launch_bounds__(256) void scatter_kernel(
    const int* __restrict__ winmap, const float* __restrict__ potwin,
    float* __restrict__ out) {
  int pos = blockIdx.x * 256 + threadIdx.x;
  if (pos >= 6400) return;
  int win = winmap[pos];
  if (win < 0) return;
#pragma unroll
  for (int t = 0; t < T_STEPS; ++t) {
    float p = potwin[t * 6400 + pos];
    int o = (t * 250 + win) * 6400 + pos;
    out[o] = (p > 0.f) ? 1.f : 0.f;
    out[24000000 + o] = p;
  }
}

// ---------------------------------------------------------------------------
extern "C" void kernel_launch(void* const* d_in, const int* in_sizes, int n_in,
                              void* d_out, int out_size, void* d_ws,
                              size_t ws_size, hipStream_t stream) {
  const int*   xin = (const int*)d_in[0];
  const float* w1  = (const float*)d_in[1];
  const float* w2  = (const float*)d_in[2];
  float* out = (float*)d_out;
  char*  ws  = (char*)d_ws;

  u16*   Whi    = (u16*)(ws + WHI_OFF);
  u16*   Wlo    = (u16*)(ws + WLO_OFF);
  u16*   spk_in = (u16*)(ws + SPKIN_OFF);
  float* maxv   = (float*)(ws + MAXV_OFF);
  int*   argm   = (int*)(ws + ARGM_OFF);
  int*   winmap = (int*)(ws + WINMAP_OFF);
  float* potwin = (float*)(ws + POTWIN_OFF);

  fill_kernel<<<2048, 256, 0, stream>>>((float4v*)d_out, 12000006);
  fill_kernel<<<740,  256, 0, stream>>>((float4v*)spk_in, 378225);

  prep_wt_kernel  <<<288,  256, 0, stream>>>(w2, Whi, Wlo);
  conv1_kernel    <<<1500, 256, 0, stream>>>(xin, w1, spk_in);
  conv2_kernel    <<<800,  512, 0, stream>>>(spk_in, Whi, Wlo, maxv, argm);
  winmap_kernel   <<<25,   256, 0, stream>>>(maxv, argm, winmap);
  recompute_kernel<<<375,  256, 0, stream>>>(spk_in, w2, winmap, potwin);
  winners_kernel  <<<1,   1024, 0, stream>>>(winmap, potwin, out + 48000000);
  scatter_kernel  <<<25,   256, 0, stream>>>(winmap, potwin, out);
}

// Round 5
// 169.550 us; speedup vs baseline: 2.2731x; 1.1332x over previous
//
#include <hip/hip_runtime.h>

// ---------------------------------------------------------------------------
// MozafariMNIST2018 SNN forward (training branch, max_layer==2) for MI355X.
//
//  4-kernel fused pipeline (was 9 — graph-node overhead + tiny-launch drain):
//   K1: conv1-MFMA || d_out zero-fill || w2 hi/lo bf16 prep || spk_in borders
//   K2: conv2 implicit-GEMM MFMA (binary bf16 x hi+lo bf16, fp32 acc)
//   K3: winmap (inlined) + exact-fp32 recompute of winner potentials
//   K4: get_k_winners (block 0) || sparse scatter (blocks 1-25)
//  All output values come from exact fp32 recompute -> absmax 0.
// ---------------------------------------------------------------------------

typedef unsigned short u16;
typedef __attribute__((ext_vector_type(8))) short short8;
typedef __attribute__((ext_vector_type(4))) float f32x4;
typedef __attribute__((ext_vector_type(4))) float float4v;

#define T_STEPS 15

// ws layout (byte offsets), all 16B aligned
#define WHI_OFF     0u         // 256*288 u16 = 147456 B
#define WLO_OFF     147456u    // 147456 B
#define SPKIN_OFF   294912u    // 15*30*82*82 u16 = 6051600 B
#define MAXV_OFF    6346512u   // 96000 f32
#define ARGM_OFF    6730512u   // 96000 i32
#define WINMAP_OFF  7114512u   // 6400 i32
#define POTWIN_OFF  7140112u   // 96000 f32 -> end 7524112

// K1 block ranges
#define N_CONV1  1500
#define N_FILL   2048
#define N_PREP   288
#define N_BORDER 18
#define K1_GRID  (N_CONV1 + N_FILL + N_PREP + N_BORDER)

static __device__ __forceinline__ u16 f2bf_rne(float f) {
  unsigned u = __float_as_uint(f);
  unsigned r = u + 0x7FFFu + ((u >> 16) & 1u);
  return (u16)(r >> 16);
}
static __device__ __forceinline__ float bf2f(u16 b) {
  return __uint_as_float(((unsigned)b) << 16);
}

// ---------------------------------------------------------------------------
// K1: conv1 (MFMA) || d_out fill || prep_wt || spk_in border ring
__global__ __launch_bounds__(256) void k1_kernel(
    const int* __restrict__ xin, const float* __restrict__ w1,
    const float* __restrict__ w2, u16* __restrict__ spk_in,
    u16* __restrict__ Whi, u16* __restrict__ Wlo,
    float4v* __restrict__ out4, int out_n4) {
  __shared__ u16 w1s[32 * 160];
  __shared__ u16 patch[6 * 20 * 20 + 320];   // + zero pad region
  __shared__ unsigned char fires[30 * 256];

  int tid = threadIdx.x;
  int b = blockIdx.x;

  if (b >= N_CONV1) {
    if (b < N_CONV1 + N_FILL) {
      // ---- d_out zero fill ----
      int i = (b - N_CONV1) * 256 + tid;
      int stride = N_FILL * 256;
      float4v z = {0.f, 0.f, 0.f, 0.f};
      for (; i < out_n4; i += stride) out4[i] = z;
    } else if (b < N_CONV1 + N_FILL + N_PREP) {
      // ---- w2 -> Whi/Wlo bf16 split ----
      int g = (b - N_CONV1 - N_FILL) * 256 + tid;   // < 73728
      int f = g / 288, k = g % 288;
      u16 h = 0, l = 0;
      if (f < 250 && k < 270) {
        float w = w2[f * 270 + k];
        h = f2bf_rne(w);
        l = f2bf_rne(w - bf2f(h));
      }
      Whi[g] = h;
      Wlo[g] = l;
    } else {
      // ---- spk_in border ring zeros (pad of 82x82) ----
      int idx = (b - N_CONV1 - N_FILL - N_PREP) * 256 + tid;
      for (int u = idx; u < 145800; u += N_BORDER * 256) {
        int tc = u / 324, i = u % 324;
        int row, col;
        if (i < 82) { row = 0; col = i; }
        else if (i < 164) { row = 81; col = i - 82; }
        else if (i < 244) { row = 1 + (i - 164); col = 0; }
        else { row = 1 + (i - 244); col = 81; }
        spk_in[(size_t)tc * 6724 + row * 82 + col] = 0;
      }
    }
    return;
  }

  // ---- conv1 + fire(15) + 2x2 OR pool -> spk_in interior ----
  int t = b / 100, tile = b % 100;
  int ty0 = (tile / 10) * 16, tx0 = (tile % 10) * 16;

  for (int idx = tid; idx < 32 * 160; idx += 256) {
    int f = idx / 160, k = idx % 160;
    w1s[idx] = (f < 30 && k < 150) ? f2bf_rne(w1[f * 150 + k]) : (u16)0;
  }
  for (int idx = tid; idx < 2720; idx += 256) {
    u16 v = 0;
    if (idx < 2400) {
      int c = idx / 400, rem = idx % 400;
      int r = rem / 20, col = rem % 20;
      int gy = ty0 + r - 2, gx = tx0 + col - 2;
      if ((unsigned)gy < 160u && (unsigned)gx < 160u)
        v = xin[((t * 6 + c) * 160 + gy) * 160 + gx] ? (u16)0x3F80 : (u16)0;
    }
    patch[idx] = v;
  }
  __syncthreads();

  int lane = tid & 63, wave = tid >> 6;
  int lrow = lane & 15, lgrp = lane >> 4;

  short8 afr[2][5];
#pragma unroll
  for (int m = 0; m < 2; ++m)
#pragma unroll
    for (int ks = 0; ks < 5; ++ks)
      afr[m][ks] =
          *(const short8*)&w1s[(m * 16 + lrow) * 160 + ks * 32 + lgrp * 8];

  int offs[5][8];
#pragma unroll
  for (int ks = 0; ks < 5; ++ks)
#pragma unroll
    for (int j = 0; j < 8; ++j) {
      int k = ks * 32 + lgrp * 8 + j;
      if (k < 150) {
        int c = k / 25, r = k % 25, ky = r / 5, kx = r % 5;
        offs[ks][j] = c * 400 + ky * 20 + kx;
      } else {
        offs[ks][j] = 2400;
      }
    }

  for (int ph = 0; ph < 4; ++ph) {
    int rrow = ph * 4 + wave;
    int pbase = rrow * 20 + lrow;
    short8 bfr[5];
#pragma unroll
    for (int ks = 0; ks < 5; ++ks)
#pragma unroll
      for (int j = 0; j < 8; ++j)
        bfr[ks][j] = (short)patch[offs[ks][j] + pbase];
    f32x4 acc0 = {0.f, 0.f, 0.f, 0.f}, acc1 = {0.f, 0.f, 0.f, 0.f};
#pragma unroll
    for (int ks = 0; ks < 5; ++ks) {
      acc0 = __builtin_amdgcn_mfma_f32_16x16x32_bf16(afr[0][ks], bfr[ks],
                                                     acc0, 0, 0, 0);
      acc1 = __builtin_amdgcn_mfma_f32_16x16x32_bf16(afr[1][ks], bfr[ks],
                                                     acc1, 0, 0, 0);
    }
#pragma unroll
    for (int r = 0; r < 4; ++r) {
      int f0 = lgrp * 4 + r;
      fires[f0 * 256 + rrow * 16 + lrow] = (acc0[r] >= 15.f);
      int f1 = 16 + lgrp * 4 + r;
      if (f1 < 30) fires[f1 * 256 + rrow * 16 + lrow] = (acc1[r] >= 15.f);
    }
  }
  __syncthreads();

  int pby0 = (ty0 >> 1) + 1, pbx0 = (tx0 >> 1) + 1;
  for (int idx = tid; idx < 30 * 64; idx += 256) {
    int f = idx >> 6, pp = idx & 63;
    int py = pp >> 3, px = pp & 7;
    const unsigned char* fb = &fires[f * 256 + py * 32 + px * 2];
    int v = fb[0] | fb[1] | fb[16] | fb[17];
    spk_in[((t * 30 + f) * 82 + pby0 + py) * 82 + pbx0 + px] =
        v ? (u16)0x3F80 : (u16)0;
  }
}

// ---------------------------------------------------------------------------
// K2: conv2 implicit-GEMM MFMA, 2 time-steps per block.
// grid 8*100, block 512 (8 waves; wave = 32 f). Tile: 256 f x 64 pos x 2 t.
__global__ __launch_bounds__(512) void conv2_kernel(
    const u16* __restrict__ spk_in, const u16* __restrict__ Whi,
    const u16* __restrict__ Wlo, float* __restrict__ maxv_ws,
    int* __restrict__ argm_ws) {
  __shared__ __align__(16) u16 lds[2 * 64 * 192 + 2 * 3000];
  u16* Xt = lds;
  u16* patch = lds + 24576;

  int tid = threadIdx.x;
  int b = blockIdx.x;
  int tp = b / 100, tile = b % 100;
  int t0 = tp * 2;
  bool has_t1 = (t0 + 1) < T_STEPS;
  int y0 = (tile / 10) * 8, x0 = (tile % 10) * 8;

  for (int idx = tid; idx < 6000; idx += 512) {
    int tt = idx / 3000, rem = idx % 3000;
    int c = rem / 100, r2 = rem % 100;
    int dy = r2 / 10, dx = r2 % 10;
    patch[idx] =
        spk_in[((size_t)(t0 + tt) * 30 + c) * 6724 + (y0 + dy) * 82 + (x0 + dx)];
  }

  int lane = tid & 63, wave = tid >> 6;
  int lrow = lane & 15, lgrp = lane >> 4;

  f32x4 acc[2][2][4];
#pragma unroll
  for (int tt = 0; tt < 2; ++tt)
#pragma unroll
    for (int i = 0; i < 2; ++i)
#pragma unroll
      for (int j = 0; j < 4; ++j) acc[tt][i][j] = (f32x4){0.f, 0.f, 0.f, 0.f};

  int xorr = (lrow & 7) << 3;

  for (int ph = 0; ph < 2; ++ph) {
    int nks = ph ? 4 : 5;
    int kbase = ph ? 160 : 0;
    int ng = nks * 4;
    __syncthreads();
    int ntask = 2 * 64 * ng;
    for (int task = tid; task < ntask; task += 512) {
      int tt = task / (64 * ng), rem = task % (64 * ng);
      int p = rem / ng, g = rem % ng;
      int py = p >> 3, px = p & 7;
      short8 sv;
#pragma unroll
      for (int j = 0; j < 8; ++j) {
        int k = kbase + g * 8 + j;
        u16 v = 0;
        if (k < 270) {
          int c = k / 9, r9 = k % 9;
          int ky = r9 / 3, kx = r9 % 3;
          v = patch[tt * 3000 + c * 100 + (py + ky) * 10 + (px + kx)];
        }
        sv[j] = (short)v;
      }
      int s = (p * 192 + g * 8) ^ ((p & 7) << 3);
      *(short8*)(Xt + tt * 12288 + s) = sv;
    }
    __syncthreads();

    const u16* wh = Whi + (wave * 32 + lrow) * 288 + kbase + lgrp * 8;
    const u16* wl = Wlo + (wave * 32 + lrow) * 288 + kbase + lgrp * 8;
    for (int ks = 0; ks < nks; ++ks) {
      short8 ahi[2], alo[2];
#pragma unroll
      for (int ft = 0; ft < 2; ++ft) {
        ahi[ft] = *(const short8*)(wh + ft * 16 * 288 + ks * 32);
        alo[ft] = *(const short8*)(wl + ft * 16 * 288 + ks * 32);
      }
#pragma unroll
      for (int tt = 0; tt < 2; ++tt) {
        short8 bfr[4];
#pragma unroll
        for (int pt = 0; pt < 4; ++pt) {
          int s = ((pt * 16 + lrow) * 192 + ks * 32 + lgrp * 8) ^ xorr;
          bfr[pt] = *(const short8*)(Xt + tt * 12288 + s);
        }
#pragma unroll
        for (int ft = 0; ft < 2; ++ft)
#pragma unroll
          for (int pt = 0; pt < 4; ++pt) {
            acc[tt][ft][pt] = __builtin_amdgcn_mfma_f32_16x16x32_bf16(
                ahi[ft], bfr[pt], acc[tt][ft][pt], 0, 0, 0);
            acc[tt][ft][pt] = __builtin_amdgcn_mfma_f32_16x16x32_bf16(
                alo[ft], bfr[pt], acc[tt][ft][pt], 0, 0, 0);
          }
      }
    }
  }

  float* redv = (float*)lds;
  int*   redi = (int*)lds + 640;
  for (int tt = 0; tt < 2; ++tt) {
    __syncthreads();
#pragma unroll
    for (int pt = 0; pt < 4; ++pt) {
      float bv = -1.f; int bf = 0;
#pragma unroll
      for (int ft = 0; ft < 2; ++ft)
#pragma unroll
        for (int r = 0; r < 4; ++r) {
          float v = acc[tt][ft][pt][r];
          v = (v >= 10.f) ? v : 0.f;
          int f = wave * 32 + ft * 16 + lgrp * 4 + r;
          if (v > bv) { bv = v; bf = f; }
        }
      {
        float ov = __shfl_xor(bv, 16); int of = __shfl_xor(bf, 16);
        if (ov > bv || (ov == bv && of < bf)) { bv = ov; bf = of; }
        ov = __shfl_xor(bv, 32); of = __shfl_xor(bf, 32);
        if (ov > bv || (ov == bv && of < bf)) { bv = ov; bf = of; }
      }
      if (lgrp == 0) {
        int p = pt * 16 + lrow;
        redv[p * 9 + wave] = bv;
        redi[p * 9 + wave] = bf;
      }
    }
    __syncthreads();
    if (tid < 64 && (tt == 0 || has_t1)) {
      float bv = -1.f; int bf = 0x7fffffff;
#pragma unroll
      for (int w = 0; w < 8; ++w) {
        float v = redv[tid * 9 + w]; int f = redi[tid * 9 + w];
        if (v > bv || (v == bv && f < bf)) { bv = v; bf = f; }
      }
      int pos = (y0 + (tid >> 3)) * 80 + x0 + (tid & 7);
      maxv_ws[(t0 + tt) * 6400 + pos] = bv;
      argm_ws[(t0 + tt) * 6400 + pos] = bf;
    }
  }
}

// ---------------------------------------------------------------------------
// K3: winmap (inlined per block) + exact fp32 recompute, LDS-staged patch.
// grid 15*25 (one t, 16x16 pos tile), block 256 (one thread per pos).
__global__ __launch_bounds__(256) void recompute_kernel(
    const u16* __restrict__ spk_in, const float* __restrict__ w2,
    const float* __restrict__ maxv, const int* __restrict__ argm,
    int* __restrict__ winmap, float* __restrict__ potwin) {
  __shared__ u16 patch[30 * 18 * 18];

  int tid = threadIdx.x;
  int b = blockIdx.x;
  int t = b / 25, tile = b % 25;
  int ty0 = (tile / 5) * 16, tx0 = (tile % 5) * 16;

  const u16* base = spk_in + (size_t)t * 30 * 6724;
  for (int idx = tid; idx < 9720; idx += 256) {
    int c = idx / 324, rem = idx % 324;
    int dy = rem / 18, dx = rem % 18;
    patch[idx] = base[c * 6724 + (ty0 + dy) * 82 + (tx0 + dx)];
  }

  int py = tid >> 4, px = tid & 15;
  int pos = (ty0 + py) * 80 + tx0 + px;

  // inline winmap (same result for every t-block over this pos)
  int nc = 0;
#pragma unroll
  for (int tt = 0; tt < T_STEPS; ++tt)
    nc += (maxv[tt * 6400 + pos] > 0.f) ? 1 : 0;
  int e = T_STEPS - nc; if (e > 14) e = 14;
  int win = argm[e * 6400 + pos];
  bool gate = maxv[14 * 6400 + pos] > 0.f;
  win = gate ? win : -1;
  if (t == 0) winmap[pos] = win;

  __syncthreads();

  float p = 0.f;
  if (win >= 0) {
    const float* wt = w2 + win * 270;
    float a = 0.f;
    for (int c = 0; c < 30; ++c) {        // exact fp32 chain (matches ref)
#pragma unroll
      for (int ky = 0; ky < 3; ++ky)
#pragma unroll
        for (int kx = 0; kx < 3; ++kx)
          a = fmaf(wt[c * 9 + ky * 3 + kx],
                   bf2f(patch[c * 324 + (py + ky) * 18 + (px + kx)]), a);
    }
    p = (a >= 10.f) ? a : 0.f;
  }
  potwin[t * 6400 + pos] = p;
}

// ---------------------------------------------------------------------------
// K4: block 0 = get_k_winners; blocks 1-25 = sparse scatter into zeroed d_out
__global__ __launch_bounds__(1024) void finalize_kernel(
    const int* __restrict__ winmap, const float* __restrict__ potwin,
    float* __restrict__ out, float* __restrict__ out_win) {
  __shared__ float tv[6400];
  __shared__ int   tf[6400];
  __shared__ float wv_s[16];
  __shared__ int   wk_s[16];
  __shared__ int   sh_w[4];
  __shared__ float vmax_s;

  int tid = threadIdx.x;
  int b = blockIdx.x;

  if (b > 0) {
    // ---- scatter: 256 positions per block, t split across 4 thread groups
    int pos = (b - 1) * 256 + (tid & 255);
    int tq = tid >> 8;
    int win = winmap[pos];
    if (win < 0) return;
    int tend = tq * 4 + 4; if (tend > T_STEPS) tend = T_STEPS;
    for (int t = tq * 4; t < tend; ++t) {
      float p = potwin[t * 6400 + pos];
      int o = (t * 250 + win) * 6400 + pos;
      out[o] = (p > 0.f) ? 1.f : 0.f;
      out[24000000 + o] = p;
    }
    return;
  }

  int lane = tid & 63, wid = tid >> 6;

  float localmax = 0.f;
  for (int pos = tid; pos < 6400; pos += 1024) {
    int win = winmap[pos];
    float val = 0.f; int nspk = 0;
    if (win >= 0) {
#pragma unroll
      for (int t = 0; t < T_STEPS; ++t)
        nspk += (potwin[t * 6400 + pos] > 0.f) ? 1 : 0;
      int first = T_STEPS - nspk; if (first > 14) first = 14;
      val = potwin[first * 6400 + pos];
      if (nspk > 0 && val > localmax) localmax = val;
    }
    tv[pos] = val;
    tf[pos] = ((win + 1) << 4) | nspk;
  }
#pragma unroll
  for (int m = 1; m < 64; m <<= 1)
    localmax = fmaxf(localmax, __shfl_xor(localmax, m));
  if (lane == 0) wv_s[wid] = localmax;
  __syncthreads();
  if (tid == 0) {
    float m = 0.f;
#pragma unroll
    for (int w = 0; w < 16; ++w) m = fmaxf(m, wv_s[w]);
    vmax_s = m * (float)T_STEPS;
  }
  __syncthreads();
  float v = vmax_s;

  for (int pos = tid; pos < 6400; pos += 1024) {
    int meta = tf[pos];
    int win = (meta >> 4) - 1, nspk = meta & 15;
    tf[pos] = win;
    tv[pos] = (win >= 0) ? (float)nspk * (tv[pos] + v) : 0.f;
  }
  __syncthreads();

  for (int it = 0; it < 8; ++it) {
    float bv = -1.f; int bk = 0x7fffffff;
    for (int pos = tid; pos < 6400; pos += 1024) {
      float tvv = tv[pos];
      int key = tf[pos] * 6400 + pos;
      if (tvv > bv || (tvv == bv && key < bk)) { bv = tvv; bk = key; }
    }
#pragma unroll
    for (int m = 1; m < 64; m <<= 1) {
      float ov = __shfl_xor(bv, m); int ok = __shfl_xor(bk, m);
      if (ov > bv || (ov == bv && ok < bk)) { bv = ov; bk = ok; }
    }
    if (lane == 0) { wv_s[wid] = bv; wk_s[wid] = bk; }
    __syncthreads();
    if (tid == 0) {
      float mbv = -1.f; int mbk = 0x7fffffff;
#pragma unroll
      for (int w = 0; w < 16; ++w) {
        float ov = wv_s[w]; int ok = wk_s[w];
        if (ov > mbv || (ov == mbv && ok < mbk)) { mbv = ov; mbk = ok; }
      }
      int f = -1, r = -1, c = -1, valid = 0;
      if (mbv != 0.f) {
        f = mbk / 6400; int pos = mbk % 6400;
        r = pos / 80; c = pos % 80;
        valid = 1;
      }
      out_win[it * 3 + 0] = (float)f;
      out_win[it * 3 + 1] = (float)r;
      out_win[it * 3 + 2] = (float)c;
      sh_w[0] = f; sh_w[1] = r; sh_w[2] = c; sh_w[3] = valid;
    }
    __syncthreads();
    if (sh_w[3]) {
      int wf = sh_w[0], wr = sh_w[1], wc = sh_w[2];
      for (int pos = tid; pos < 6400; pos += 1024) {
        int r = pos / 80, c = pos % 80;
        int dr = r - wr; if (dr < 0) dr = -dr;
        int dc = c - wc; if (dc < 0) dc = -dc;
        if (tf[pos] == wf || (dr <= 1 && dc <= 1)) tv[pos] = 0.f;
      }
    }
    __syncthreads();
  }
}

// ---------------------------------------------------------------------------
extern "C" void kernel_launch(void* const* d_in, const int* in_sizes, int n_in,
                              void* d_out, int out_size, void* d_ws,
                              size_t ws_size, hipStream_t stream) {
  const int*   xin = (const int*)d_in[0];
  const float* w1  = (const float*)d_in[1];
  const float* w2  = (const float*)d_in[2];
  float* out = (float*)d_out;
  char*  ws  = (char*)d_ws;

  u16*   Whi    = (u16*)(ws + WHI_OFF);
  u16*   Wlo    = (u16*)(ws + WLO_OFF);
  u16*   spk_in = (u16*)(ws + SPKIN_OFF);
  float* maxv   = (float*)(ws + MAXV_OFF);
  int*   argm   = (int*)(ws + ARGM_OFF);
  int*   winmap = (int*)(ws + WINMAP_OFF);
  float* potwin = (float*)(ws + POTWIN_OFF);

  k1_kernel<<<K1_GRID, 256, 0, stream>>>(xin, w1, w2, spk_in, Whi, Wlo,
                                         (float4v*)d_out, out_size / 4);
  conv2_kernel<<<800, 512, 0, stream>>>(spk_in, Whi, Wlo, maxv, argm);
  recompute_kernel<<<375, 256, 0, stream>>>(spk_in, w2, maxv, argm, winmap,
                                            potwin);
  finalize_kernel<<<26, 1024, 0, stream>>>(winmap, potwin, out,
                                           out + 48000000);
}